// Round 14
// baseline (248.477 us; speedup 1.0000x reference)
//
#include <hip/hip_runtime.h>

typedef unsigned short u16;
typedef __bf16 bf16x8 __attribute__((ext_vector_type(8)));
typedef float f32x4 __attribute__((ext_vector_type(4)));
typedef u16 u16x8 __attribute__((ext_vector_type(8)));
typedef u16 u16x4 __attribute__((ext_vector_type(4)));

#define B_ 16384

__device__ __forceinline__ u16 f2b(float f){
  unsigned u = __builtin_bit_cast(unsigned, f);
  u = (u + 0x7FFFu + ((u >> 16) & 1u)) >> 16;   // RNE
  return (u16)u;
}
__device__ __forceinline__ float b2f(u16 v){
  return __builtin_bit_cast(float, ((unsigned)v) << 16);
}
__device__ __forceinline__ void ld8(const u16* __restrict__ p, float* f){
  u16x8 v = *(const u16x8*)p;
  #pragma unroll
  for (int j = 0; j < 8; ++j) f[j] = b2f(v[j]);
}
__device__ __forceinline__ void st8(u16* __restrict__ p, const float* f){
  u16x8 v;
  #pragma unroll
  for (int j = 0; j < 8; ++j) v[j] = f2b(f[j]);
  *(u16x8*)p = v;
}

__device__ __forceinline__ void gload16(const u16* g, u16* lds){
  __builtin_amdgcn_global_load_lds(
      (const __attribute__((address_space(1))) unsigned int*)g,
      (__attribute__((address_space(3))) unsigned int*)lds, 16, 0, 0);
}

// ===== core32 (R9/R10-proven): BM=256, BN=128, BK=32, ring-3, counted vmcnt =
__device__ __forceinline__ void core32(const u16* __restrict__ A,
                                       const u16* __restrict__ Wt,
                                       int K, int m0, int n0, int nt,
                                       u16* sm, f32x4 acc[4][4])
{
  const int tid = threadIdx.x, lane = tid & 63, wave = tid >> 6;
  const int wm = ((tid >> 7) & 3) * 64;
  const int wn = ((tid >> 6) & 1) * 64;

  #pragma unroll
  for (int m = 0; m < 4; ++m)
    #pragma unroll
    for (int n = 0; n < 4; ++n) acc[m][n] = (f32x4){0.f, 0.f, 0.f, 0.f};

  const int s_    = (lane & 7) ^ ((lane >> 3) & 7);
  const int srow2 = 2 * (lane >> 3) + (s_ >> 2);
  const int sk    = (s_ & 3) * 8;
  const u16* gsrc[3];
  int gdst[3];
  #pragma unroll
  for (int i = 0; i < 3; ++i) {
    int c = wave * 3 + i;
    if (c < 16) {
      gsrc[i] = A + (size_t)(m0 + c * 16 + srow2) * K + sk;
      gdst[i] = c * 512;
    } else {
      gsrc[i] = Wt + (size_t)(n0 + (c - 16) * 16 + srow2) * K + sk;
      gdst[i] = 8192 + (c - 16) * 512;
    }
  }

  int aoff[4], boff[4];
  #pragma unroll
  for (int m = 0; m < 4; ++m) {
    int r = wm + m * 16 + (lane & 15);
    int L = r >> 1;
    int phys = (((r & 1) << 2) + (lane >> 4)) ^ (L & 7);
    aoff[m] = L * 64 + phys * 8;
  }
  #pragma unroll
  for (int n = 0; n < 4; ++n) {
    int r = wn + n * 16 + (lane & 15);
    int L = r >> 1;
    int phys = (((r & 1) << 2) + (lane >> 4)) ^ (L & 7);
    boff[n] = 8192 + L * 64 + phys * 8;
  }

  #pragma unroll
  for (int j = 0; j < 2; ++j) {
    u16* sl = sm + j * 12288;
    #pragma unroll
    for (int i = 0; i < 3; ++i) gload16(gsrc[i] + j * 32, sl + gdst[i]);
  }
  asm volatile("s_waitcnt vmcnt(3)" ::: "memory");
  __builtin_amdgcn_s_barrier();

  int cs = 0;
  for (int j = 0; j < nt; ++j) {
    if (j + 2 < nt) {
      int ns = cs + 2; ns = (ns >= 3) ? ns - 3 : ns;
      u16* sl = sm + ns * 12288;
      #pragma unroll
      for (int i = 0; i < 3; ++i) gload16(gsrc[i] + (size_t)(j + 2) * 32, sl + gdst[i]);
    }
    const u16* sa = sm + cs * 12288;
    bf16x8 av[4], bv[4];
    #pragma unroll
    for (int m = 0; m < 4; ++m) av[m] = *(const bf16x8*)(sa + aoff[m]);
    #pragma unroll
    for (int n = 0; n < 4; ++n) bv[n] = *(const bf16x8*)(sa + boff[n]);
    __builtin_amdgcn_s_setprio(1);
    #pragma unroll
    for (int m = 0; m < 4; ++m)
      #pragma unroll
      for (int n = 0; n < 4; ++n)
        acc[m][n] = __builtin_amdgcn_mfma_f32_16x16x32_bf16(av[m], bv[n], acc[m][n], 0, 0, 0);
    __builtin_amdgcn_s_setprio(0);
    if (j + 2 < nt)      asm volatile("s_waitcnt vmcnt(3)" ::: "memory");
    else if (j + 1 < nt) asm volatile("s_waitcnt vmcnt(0)" ::: "memory");
    __builtin_amdgcn_s_barrier();
    cs = (cs == 2) ? 0 : cs + 1;
  }
}

// ---------------- stage kernels ----------------

// GATE0 (R6-proven): 26 gate logits per row + softmax -> G0S[16384][32].
// [0..15] task gates (t*4+i), [16..25] all-expert shared gates.
__global__ __launch_bounds__(256) void k_gate0(const u16* __restrict__ xb,
    const u16* __restrict__ WG0T, const float* __restrict__ b_gate0,
    const float* __restrict__ b_gsh0, float* __restrict__ G0S)
{
  const int lane = threadIdx.x & 63, wave = threadIdx.x >> 6;
  const int rbase = blockIdx.x * 64 + wave * 16;
  u16x8 w[26];
  #pragma unroll
  for (int g = 0; g < 26; ++g)
    w[g] = *(const u16x8*)(WG0T + (size_t)g * 512 + lane * 8);
  float bias[26];
  #pragma unroll
  for (int g = 0; g < 26; ++g) bias[g] = (g < 16) ? b_gate0[g] : b_gsh0[g - 16];

  for (int it = 0; it < 16; ++it) {
    int row = rbase + it;
    float f[8]; ld8(xb + (size_t)row * 512 + lane * 8, f);
    float lg[26];
    #pragma unroll
    for (int g = 0; g < 26; ++g) {
      float p = 0.f;
      #pragma unroll
      for (int j = 0; j < 8; ++j) p += f[j] * b2f(w[g][j]);
      #pragma unroll
      for (int off = 1; off < 64; off <<= 1) p += __shfl_xor(p, off);
      lg[g] = p + bias[g];
    }
    float tg[16];
    #pragma unroll
    for (int t = 0; t < 4; ++t) {
      float m = fmaxf(fmaxf(lg[4*t], lg[4*t+1]), fmaxf(lg[4*t+2], lg[4*t+3]));
      float e0 = expf(lg[4*t]-m), e1 = expf(lg[4*t+1]-m);
      float e2 = expf(lg[4*t+2]-m), e3 = expf(lg[4*t+3]-m);
      float inv = 1.f / (e0+e1+e2+e3);
      tg[4*t] = e0*inv; tg[4*t+1] = e1*inv; tg[4*t+2] = e2*inv; tg[4*t+3] = e3*inv;
    }
    float sg[10];
    {
      float m = lg[16];
      #pragma unroll
      for (int j = 1; j < 10; ++j) m = fmaxf(m, lg[16+j]);
      float ssum = 0.f;
      #pragma unroll
      for (int j = 0; j < 10; ++j) { sg[j] = expf(lg[16+j]-m); ssum += sg[j]; }
      float inv = 1.f / ssum;
      #pragma unroll
      for (int j = 0; j < 10; ++j) sg[j] *= inv;
    }
    float* orow = G0S + (size_t)row * 32;
    #pragma unroll
    for (int g = 0; g < 16; ++g) if (lane == g) orow[g] = tg[g];
    #pragma unroll
    for (int j = 0; j < 10; ++j) if (lane == 16 + j) orow[16 + j] = sg[j];
  }
}

// GEMM0SH: xb x WT0S[512,512]^T -> SH0E (shared expert acts, bf16).
__global__ __launch_bounds__(512) void k_gemm0sh(const u16* __restrict__ xb,
    const u16* __restrict__ WT0S, const float* __restrict__ bias0s,
    u16* __restrict__ SH0E)
{
  __shared__ __align__(16) u16 sm[36864];
  f32x4 acc[4][4];
  const int bid = blockIdx.x;                 // 256 = 8 * 32
  const int swz = (bid & 7) * 32 + (bid >> 3);
  const int m0 = (swz >> 2) * 256, n0 = (swz & 3) * 128;
  core32(xb, WT0S, 512, m0, n0, 16, sm, acc);
  const int lane = threadIdx.x & 63;
  const int wm = ((threadIdx.x >> 7) & 3) * 64, wn = ((threadIdx.x >> 6) & 1) * 64;
  #pragma unroll
  for (int mi = 0; mi < 4; ++mi)
    #pragma unroll
    for (int ni = 0; ni < 4; ++ni) {
      int gcol = n0 + wn + ni * 16 + (lane & 15);
      float bias = bias0s[gcol];
      #pragma unroll
      for (int q = 0; q < 4; ++q) {
        int grow = m0 + wm + mi * 16 + ((lane >> 4) << 2) + q;
        SH0E[(size_t)grow * 512 + gcol] = f2b(fmaxf(acc[mi][ni][q] + bias, 0.f));
      }
    }
}

// GEMM0T: task experts e-major (col = e*8 + te) + IN-BLOCK MIXING epilogue.
// Main loop: core32 on WT0T[2048,512]. Epilogue per half (2 mi planes):
//   phase A: relu+bias acc -> LDS scratch [128 rows][16e x 9 f32] (pad 9/el);
//   phase B: thread (r,p) mixes 4 e: t1[t] = g.. , shacc; writes T1SH directly.
// E0 and mix0 are eliminated.
__global__ __launch_bounds__(512) void k_gemm0t(const u16* __restrict__ xb,
    const u16* __restrict__ WT0T, const float* __restrict__ bias0t,
    const u16* __restrict__ SH0E, const float* __restrict__ G0S,
    u16* __restrict__ T1SH)
{
  __shared__ __align__(16) u16 sm[36864];
  f32x4 acc[4][4];
  const int bid = blockIdx.x;                 // 1024 = 8 * 128
  const int swz = (bid & 7) * 128 + (bid >> 3);
  const int m0 = (swz >> 4) * 256, n0 = (swz & 15) * 128;
  core32(xb, WT0T, 512, m0, n0, 16, sm, acc);

  const int tid = threadIdx.x, lane = tid & 63;
  const int wmIdx = (tid >> 7) & 3;
  const int wn = ((tid >> 6) & 1) * 64;
  float* lds2 = (float*)sm;                   // 128 x 136 f32 = 69632 B <= 73728
  const int ebase = n0 >> 3;                  // 16 e per 128-col panel

  for (int pair = 0; pair < 2; ++pair) {
    __syncthreads();
    // phase A: two mi planes -> LDS (relu + bias applied)
    #pragma unroll
    for (int mi2 = 0; mi2 < 2; ++mi2) {
      int mi = pair * 2 + mi2;
      #pragma unroll
      for (int ni = 0; ni < 4; ++ni) {
        int colL = wn + ni * 16 + (lane & 15);
        float bias = bias0t[n0 + colL];
        int el = colL >> 3, s2 = colL & 7;
        #pragma unroll
        for (int q = 0; q < 4; ++q) {
          int rl = wmIdx * 32 + mi2 * 16 + ((lane >> 4) << 2) + q;
          lds2[rl * 136 + el * 9 + s2] = fmaxf(acc[mi][ni][q] + bias, 0.f);
        }
      }
    }
    __syncthreads();
    // phase B: mix. thread -> (row r, e-quarter p)
    const int r = tid >> 2, p = tid & 3;
    const int grow = m0 + (r >> 5) * 64 + pair * 32 + (r & 31);
    const float* gp = G0S + (size_t)grow * 32;
    u16x4 o[5];
    #pragma unroll
    for (int k = 0; k < 4; ++k) {
      int el = p * 4 + k;
      float ex[8];
      #pragma unroll
      for (int s2 = 0; s2 < 8; ++s2) ex[s2] = lds2[r * 136 + el * 9 + s2];
      int eg = ebase + el;
      float sh0v = b2f(SH0E[(size_t)grow * 512 + eg]);
      float sh1v = b2f(SH0E[(size_t)grow * 512 + 256 + eg]);
      float sha = gp[24] * sh0v + gp[25] * sh1v;
      #pragma unroll
      for (int t = 0; t < 4; ++t) {
        float v = gp[t*4+0] * ex[2*t] + gp[t*4+1] * ex[2*t+1]
                + gp[t*4+2] * sh0v    + gp[t*4+3] * sh1v;
        o[t][k] = f2b(v);
        sha += gp[16 + 2*t] * ex[2*t] + gp[17 + 2*t] * ex[2*t+1];
      }
      o[4][k] = f2b(sha);
    }
    int eg0 = ebase + p * 4;
    #pragma unroll
    for (int t = 0; t < 5; ++t)
      *(u16x4*)(T1SH + ((size_t)t * B_ + grow) * 256 + eg0) = o[t];
  }
}

// GATE1: 16 level-1 gate logits per row from t1 (mix0's proven tail) -> G1S.
__global__ __launch_bounds__(256) void k_gate1(const u16* __restrict__ T1SH,
    const float* __restrict__ WG1T, const float* __restrict__ b_gate1,
    float* __restrict__ G1S)
{
  const int b = blockIdx.x * 8 + (threadIdx.x >> 5);
  const int e0 = (threadIdx.x & 31) * 8;
  float gp[16];
  #pragma unroll
  for (int t = 0; t < 4; ++t) {
    float v[8];
    ld8(T1SH + ((size_t)t * B_ + b) * 256 + e0, v);
    #pragma unroll
    for (int gg = 0; gg < 4; ++gg) {
      const float* wv = WG1T + ((size_t)(t * 4 + gg) * 256 + e0);
      float s = 0.f;
      #pragma unroll
      for (int j = 0; j < 8; ++j) s += v[j] * wv[j];
      gp[t * 4 + gg] = s;
    }
  }
  #pragma unroll
  for (int i = 0; i < 16; ++i) {
    #pragma unroll
    for (int off = 1; off < 32; off <<= 1)
      gp[i] += __shfl_xor(gp[i], off, 32);
  }
  if ((threadIdx.x & 31) == 0) {
    float* orow = G1S + (size_t)b * 16;
    #pragma unroll
    for (int z = 0; z < 4; ++z) {
      float l0 = gp[z*4+0] + b_gate1[z*4+0];
      float l1 = gp[z*4+1] + b_gate1[z*4+1];
      float l2 = gp[z*4+2] + b_gate1[z*4+2];
      float l3 = gp[z*4+3] + b_gate1[z*4+3];
      float m = fmaxf(fmaxf(l0, l1), fmaxf(l2, l3));
      float x0 = expf(l0-m), x1 = expf(l1-m), x2 = expf(l2-m), x3 = expf(l3-m);
      float inv = 1.f / (x0 + x1 + x2 + x3);
      orow[z*4+0] = x0*inv; orow[z*4+1] = x1*inv;
      orow[z*4+2] = x2*inv; orow[z*4+3] = x3*inv;
    }
  }
}

// GEMM1 (R10-proven): 20 panels (z 0..4 x 4 n-tiles of 128) x 64 m-blocks.
__global__ __launch_bounds__(512) void k_gemm1(const u16* __restrict__ T1SH,
    const u16* __restrict__ Wt1, const float* __restrict__ bias1,
    u16* __restrict__ E1, u16* __restrict__ SH1E)
{
  __shared__ __align__(16) u16 sm[36864];
  f32x4 acc[4][4];
  const int bid = blockIdx.x;                 // 1280 = 8 * 160
  const int swz = (bid & 7) * 160 + (bid >> 3);
  const int mi_ = swz / 20, pan = swz % 20;
  const int z  = pan >> 2;
  const int n0 = (pan & 3) * 128;
  const int m0 = mi_ * 256;
  core32(T1SH + (size_t)z * B_ * 256, Wt1 + (size_t)z * 512 * 256, 256, m0, n0, 8, sm, acc);
  const int lane = threadIdx.x & 63;
  const int wm = ((threadIdx.x >> 7) & 3) * 64, wn = ((threadIdx.x >> 6) & 1) * 64;
  const float* bias = bias1 + z * 512;
  #pragma unroll
  for (int mi = 0; mi < 4; ++mi)
    #pragma unroll
    for (int ni = 0; ni < 4; ++ni) {
      int gcol = n0 + wn + ni * 16 + (lane & 15);
      float bv = bias[gcol];
      #pragma unroll
      for (int q = 0; q < 4; ++q) {
        int grow = m0 + wm + mi * 16 + ((lane >> 4) << 2) + q;
        float v = fmaxf(acc[mi][ni][q] + bv, 0.f);
        if (z < 4) E1[((size_t)z * B_ + grow) * 512 + gcol] = f2b(v);
        else       SH1E[(size_t)grow * 512 + gcol] = f2b(v);
      }
    }
}

// TOWER2 (mix1 fused, R10-proven): A-tile = t2[z] built during reg-staging.
__global__ __launch_bounds__(256) void k_tower2(const u16* __restrict__ E1,
    const u16* __restrict__ SH1E, const float* __restrict__ G1S,
    const u16* __restrict__ Wtw, const float* __restrict__ b_tw,
    const float* __restrict__ w_out, const float* __restrict__ b_out,
    float* __restrict__ out)
{
  __shared__ __align__(16) u16 sm[32768];
  __shared__ float part[2][128][2];
  f32x4 acc[4][4];
  const int z = blockIdx.z;
  const int m0 = blockIdx.x * 128;
  const int tid = threadIdx.x, lane = tid & 63, wave = tid >> 6;
  const int wm = ((tid >> 7) & 1) * 64, wn = ((tid >> 6) & 1) * 64;

  #pragma unroll
  for (int mi = 0; mi < 4; ++mi)
    #pragma unroll
    for (int ni = 0; ni < 4; ++ni) acc[mi][ni] = (f32x4){0.f, 0.f, 0.f, 0.f};

  const int srow  = lane >> 3;
  const int gslot = (lane & 7) ^ srow;
  const int koff0 = gslot * 8;

  int growA[4], adst[4], bdst[4];
  const u16* bsrc[4];
  #pragma unroll
  for (int i = 0; i < 4; ++i) {
    int c = wave * 4 + i;
    growA[i] = m0 + c * 8 + srow;
    adst[i]  = c * 512;
    bsrc[i]  = Wtw + (size_t)z * 128 * 256 + (size_t)(c * 8 + srow) * 256 + koff0;
    bdst[i]  = 8192 + c * 512;
  }
  const u16* E1z = E1 + (size_t)z * B_ * 512;

  int aoff[2][4], boff[2][4];
  #pragma unroll
  for (int kk = 0; kk < 2; ++kk) {
    #pragma unroll
    for (int m = 0; m < 4; ++m) {
      int r = wm + m * 16 + (lane & 15);
      aoff[kk][m] = r * 64 + (((kk * 4 + (lane >> 4)) ^ (r & 7)) * 8);
    }
    #pragma unroll
    for (int n = 0; n < 4; ++n) {
      int r = wn + n * 16 + (lane & 15);
      boff[kk][n] = 8192 + r * 64 + (((kk * 4 + (lane >> 4)) ^ (r & 7)) * 8);
    }
  }

  #define STAGE_T(J, BUF) do {                                                 \
    u16* buf_ = (BUF);                                                         \
    _Pragma("unroll")                                                          \
    for (int i_ = 0; i_ < 4; ++i_) {                                           \
      size_t eoff_ = (size_t)growA[i_] * 512 + (J) * 64 + koff0;               \
      u16x8 ea_ = *(const u16x8*)(E1z + eoff_);                                \
      u16x8 eb_ = *(const u16x8*)(E1z + eoff_ + 256);                          \
      u16x8 sa_ = *(const u16x8*)(SH1E + eoff_);                               \
      u16x8 sb_ = *(const u16x8*)(SH1E + eoff_ + 256);                         \
      float4 g_ = *(const float4*)(G1S + (size_t)growA[i_] * 16 + z * 4);      \
      u16x8 o_;                                                                \
      _Pragma("unroll")                                                        \
      for (int jj_ = 0; jj_ < 8; ++jj_)                                        \
        o_[jj_] = f2b(g_.x * b2f(ea_[jj_]) + g_.y * b2f(eb_[jj_])              \
                    + g_.z * b2f(sa_[jj_]) + g_.w * b2f(sb_[jj_]));            \
      *(uint4*)(buf_ + adst[i_] + lane * 8) = __builtin_bit_cast(uint4, o_);   \
      gload16(bsrc[i_] + (J) * 64, buf_ + bdst[i_]);                           \
    }                                                                          \
  } while (0)

  STAGE_T(0, sm);
  __syncthreads();

  #pragma unroll
  for (int t = 0; t < 4; ++t) {
    if (t + 1 < 4) STAGE_T(t + 1, sm + ((t + 1) & 1) * 16384);
    const u16* sa = sm + (t & 1) * 16384;
    #pragma unroll
    for (int kk = 0; kk < 2; ++kk) {
      bf16x8 av[4], bv[4];
      #pragma unroll
      for (int m = 0; m < 4; ++m) av[m] = *(const bf16x8*)(sa + aoff[kk][m]);
      #pragma unroll
      for (int n = 0; n < 4; ++n) bv[n] = *(const bf16x8*)(sa + boff[kk][n]);
      #pragma unroll
      for (int m = 0; m < 4; ++m)
        #pragma unroll
        for (int n = 0; n < 4; ++n)
          acc[m][n] = __builtin_amdgcn_mfma_f32_16x16x32_bf16(av[m], bv[n], acc[m][n], 0, 0, 0);
    }
    if (t + 1 < 4) __syncthreads();
  }
  #undef STAGE_T

  #pragma unroll
  for (int mi = 0; mi < 4; ++mi) {
    #pragma unroll
    for (int r = 0; r < 4; ++r) {
      float p0 = 0.f, p1 = 0.f;
      #pragma unroll
      for (int ni = 0; ni < 4; ++ni) {
        int col = wn + ni * 16 + (lane & 15);
        float h = fmaxf(acc[mi][ni][r] + b_tw[z * 128 + col], 0.f);
        p0 += h * w_out[(z * 128 + col) * 2 + 0];
        p1 += h * w_out[(z * 128 + col) * 2 + 1];
      }
      #pragma unroll
      for (int off = 1; off < 16; off <<= 1) {
        p0 += __shfl_xor(p0, off);
        p1 += __shfl_xor(p1, off);
      }
      if ((lane & 15) == 0) {
        int rowl = wm + mi * 16 + ((lane >> 4) << 2) + r;
        part[wn >> 6][rowl][0] = p0;
        part[wn >> 6][rowl][1] = p1;
      }
    }
  }
  __syncthreads();
  if (threadIdx.x < 128) {
    int rowl = threadIdx.x;
    float l0 = part[0][rowl][0] + part[1][rowl][0] + b_out[z * 2 + 0];
    float l1 = part[0][rowl][1] + part[1][rowl][1] + b_out[z * 2 + 1];
    float mx = fmaxf(l0, l1);
    float e0 = expf(l0 - mx), e1 = expf(l1 - mx);
    float inv = 1.f / (e0 + e1);
    float p0 = fminf(fmaxf(e0 * inv, 1e-15f), 1.0f);
    float p1 = fminf(fmaxf(e1 * inv, 1e-15f), 1.0f);
    size_t o = ((size_t)z * B_ + m0 + rowl) * 2;
    out[o] = p0; out[o + 1] = p1;
  }
}

// PREP: cast x -> bf16; e-major task panel WT0T, shared panel WT0S, gate
// panels WG0T/WG1T, WT1, WTW + bias vectors.
__global__ void k_prep(const float* __restrict__ x,
    const float* __restrict__ w_task0, const float* __restrict__ b_task0,
    const float* __restrict__ w_sh0,   const float* __restrict__ b_sh0,
    const float* __restrict__ w_gate0, const float* __restrict__ w_gsh0,
    const float* __restrict__ w_task1, const float* __restrict__ b_task1,
    const float* __restrict__ w_sh1,   const float* __restrict__ b_sh1,
    const float* __restrict__ w_gate1, const float* __restrict__ w_tw,
    u16* __restrict__ xb, u16* __restrict__ WT0T, float* __restrict__ bias0t,
    u16* __restrict__ WT0S, float* __restrict__ bias0s,
    u16* __restrict__ WG0T, u16* __restrict__ Wt1, float* __restrict__ bias1,
    u16* __restrict__ Wtw, float* __restrict__ WG1T)
{
  size_t i = (size_t)blockIdx.x * 256 + threadIdx.x;
  const size_t S_X8  = (size_t)16384 * 512 / 8; // 1048576
  const size_t S_T   = (size_t)2048 * 512;      // 1048576
  const size_t S_BT  = 2048;
  const size_t S_S   = (size_t)512 * 512;       // 262144
  const size_t S_BS  = 512;
  const size_t S_WG0 = 26 * 512;                // 13312
  const size_t S_WT1 = (size_t)5 * 512 * 256;   // 655360
  const size_t S_B1  = 5 * 512;                 // 2560
  const size_t S_WTW = (size_t)4 * 128 * 256;   // 131072
  const size_t S_WG1 = 4096;

  if (i < S_X8) {
    size_t o = i * 8;
    float4 a = *(const float4*)(x + o);
    float4 b = *(const float4*)(x + o + 4);
    u16x8 v;
    v[0] = f2b(a.x); v[1] = f2b(a.y); v[2] = f2b(a.z); v[3] = f2b(a.w);
    v[4] = f2b(b.x); v[5] = f2b(b.y); v[6] = f2b(b.z); v[7] = f2b(b.w);
    *(u16x8*)(xb + o) = v;
    return;
  }
  i -= S_X8;
  if (i < S_T) {       // e-major task experts: col c = e*8 + te
    int c = (int)(i / 512), f = (int)(i % 512);
    int te = c & 7, e = c >> 3;
    WT0T[i] = f2b(w_task0[((size_t)te * 512 + f) * 256 + e]);
    return;
  }
  i -= S_T;
  if (i < S_BT) {
    int te = (int)i & 7, e = (int)i >> 3;
    bias0t[i] = b_task0[te * 256 + e];
    return;
  }
  i -= S_BT;
  if (i < S_S) {
    int c = (int)(i / 512), f = (int)(i % 512);
    int s = c >> 8, e = c & 255;
    WT0S[i] = f2b(w_sh0[((size_t)s * 512 + f) * 256 + e]);
    return;
  }
  i -= S_S;
  if (i < S_BS) {
    int s = (int)i >> 8, e = (int)i & 255;
    bias0s[i] = b_sh0[s * 256 + e];
    return;
  }
  i -= S_BS;
  if (i < S_WG0) {
    int g = (int)(i / 512), f = (int)(i % 512);
    float v;
    if (g < 16) { int t = g >> 2, gg = g & 3; v = w_gate0[((size_t)t * 512 + f) * 4 + gg]; }
    else        { v = w_gsh0[(size_t)f * 10 + (g - 16)]; }
    WG0T[i] = f2b(v);
    return;
  }
  i -= S_WG0;
  if (i < S_WT1) {
    int z = (int)(i / (512 * 256)); int rem = (int)(i % (512 * 256));
    int c = rem / 256, f = rem % 256;
    float v;
    if (z < 4) { int ee = c >> 8, o = c & 255; v = w_task1[(((size_t)(z * 2 + ee)) * 256 + f) * 256 + o]; }
    else       { int s = c >> 8, o = c & 255; v = w_sh1[((size_t)s * 256 + f) * 256 + o]; }
    Wt1[i] = f2b(v);
    return;
  }
  i -= S_WT1;
  if (i < S_B1) {
    int z = (int)(i / 512); int c = (int)(i % 512);
    float v;
    if (z < 4) { int ee = c >> 8, o = c & 255; v = b_task1[(z * 2 + ee) * 256 + o]; }
    else       { int s = c >> 8, o = c & 255; v = b_sh1[s * 256 + o]; }
    bias1[(size_t)z * 512 + c] = v;
    return;
  }
  i -= S_B1;
  if (i < S_WTW) {
    int z = (int)(i / (128 * 256)); int rem = (int)(i % (128 * 256));
    int h = rem / 256, f = rem % 256;
    Wtw[i] = f2b(w_tw[((size_t)z * 256 + f) * 128 + h]);
    return;
  }
  i -= S_WTW;
  if (i < S_WG1) {
    int t = (int)(i >> 10), gg = (int)((i >> 8) & 3), e = (int)(i & 255);
    WG1T[i] = w_gate1[((size_t)t * 256 + e) * 4 + gg];
    return;
  }
}

extern "C" void kernel_launch(void* const* d_in, const int* in_sizes, int n_in,
                              void* d_out, int out_size, void* d_ws, size_t ws_size,
                              hipStream_t stream)
{
  (void)in_sizes; (void)n_in; (void)out_size; (void)ws_size;
  const float* x       = (const float*)d_in[0];
  const float* w_task0 = (const float*)d_in[1];
  const float* b_task0 = (const float*)d_in[2];
  const float* w_sh0   = (const float*)d_in[3];
  const float* b_sh0   = (const float*)d_in[4];
  const float* w_gate0 = (const float*)d_in[5];
  const float* b_gate0 = (const float*)d_in[6];
  const float* w_gsh0  = (const float*)d_in[7];
  const float* b_gsh0  = (const float*)d_in[8];
  const float* w_task1 = (const float*)d_in[9];
  const float* b_task1 = (const float*)d_in[10];
  const float* w_sh1   = (const float*)d_in[11];
  const float* b_sh1   = (const float*)d_in[12];
  const float* w_gate1 = (const float*)d_in[13];
  const float* b_gate1 = (const float*)d_in[14];
  const float* w_tw    = (const float*)d_in[15];
  const float* b_tw    = (const float*)d_in[16];
  const float* w_out   = (const float*)d_in[17];
  const float* b_out   = (const float*)d_in[18];
  float* out = (float*)d_out;

  char* ws = (char*)d_ws;
  u16*   XB    = (u16*)  (ws + 0);            //  16,777,216  [16384][512]
  u16*   SH1E  = (u16*)  (ws + 0);            //  reuses XB (first write: gemm1)
  u16*   WT0T  = (u16*)  (ws + 16777216);     //   2,097,152  [2048][512] e-major
  float* BIAS0T= (float*)(ws + 18874368);     //       8,192  [2048]
  u16*   WT0S  = (u16*)  (ws + 18882560);     //     524,288  [512][512]
  float* BIAS0S= (float*)(ws + 19406848);     //       2,048  [512]
  u16*   WG0T  = (u16*)  (ws + 19408896);     //      26,624  [26][512]
  u16*   WT1   = (u16*)  (ws + 19435520);     //   1,310,720  [5][512][256]
  float* BIAS1 = (float*)(ws + 20746240);     //      10,240  [5][512]
  u16*   WTW   = (u16*)  (ws + 20756480);     //     262,144  [4][128][256]
  float* WG1T  = (float*)(ws + 21018624);     //      16,384  [4][4][256]
  u16*   SH0E  = (u16*)  (ws + 21035008);     //  16,777,216  [16384][512]
  float* G0S   = (float*)(ws + 37812224);     //   2,097,152  [16384][32]
  u16*   T1SH  = (u16*)  (ws + 39909376);     //  41,943,040  [5][16384][256]
  u16*   E1    = (u16*)  (ws + 81852416);     //  67,108,864  [4][16384][512]
  float* G1S   = (float*)(ws + 148961280);    //   1,048,576  [16384][16]

  k_prep<<<12376, 256, 0, stream>>>(x, w_task0, b_task0, w_sh0, b_sh0,
      w_gate0, w_gsh0, w_task1, b_task1, w_sh1, b_sh1, w_gate1, w_tw,
      XB, WT0T, BIAS0T, WT0S, BIAS0S, WG0T, WT1, BIAS1, WTW, WG1T);
  k_gate0<<<256, 256, 0, stream>>>(XB, WG0T, b_gate0, b_gsh0, G0S);
  k_gemm0sh<<<256, 512, 0, stream>>>(XB, WT0S, BIAS0S, SH0E);
  k_gemm0t<<<1024, 512, 0, stream>>>(XB, WT0T, BIAS0T, SH0E, G0S, T1SH);
  k_gate1<<<2048, 256, 0, stream>>>(T1SH, WG1T, b_gate1, G1S);
  k_gemm1<<<1280, 512, 0, stream>>>(T1SH, WT1, BIAS1, E1, SH1E);
  k_tower2<<<dim3(128, 1, 4), 256, 0, stream>>>(E1, SH1E, G1S, WTW, b_tw, w_out, b_out, out);
}

// Round 15
// 176.613 us; speedup vs baseline: 1.4069x; 1.4069x over previous
//
#include <hip/hip_runtime.h>

typedef unsigned short u16;
typedef __bf16 bf16x8 __attribute__((ext_vector_type(8)));
typedef float f32x4 __attribute__((ext_vector_type(4)));
typedef u16 u16x8 __attribute__((ext_vector_type(8)));
typedef u16 u16x4 __attribute__((ext_vector_type(4)));

#define B_ 16384

__device__ __forceinline__ u16 f2b(float f){
  unsigned u = __builtin_bit_cast(unsigned, f);
  u = (u + 0x7FFFu + ((u >> 16) & 1u)) >> 16;   // RNE
  return (u16)u;
}
__device__ __forceinline__ float b2f(u16 v){
  return __builtin_bit_cast(float, ((unsigned)v) << 16);
}
__device__ __forceinline__ void ld8(const u16* __restrict__ p, float* f){
  u16x8 v = *(const u16x8*)p;
  #pragma unroll
  for (int j = 0; j < 8; ++j) f[j] = b2f(v[j]);
}

__device__ __forceinline__ void gload16(const u16* g, u16* lds){
  __builtin_amdgcn_global_load_lds(
      (const __attribute__((address_space(1))) unsigned int*)g,
      (__attribute__((address_space(3))) unsigned int*)lds, 16, 0, 0);
}

// ===== core32 (R9/R10-proven): BM=256, BN=128, BK=32, ring-3, counted vmcnt =
__device__ __forceinline__ void core32(const u16* __restrict__ A,
                                       const u16* __restrict__ Wt,
                                       int K, int m0, int n0, int nt,
                                       u16* sm, f32x4 acc[4][4])
{
  const int tid = threadIdx.x, lane = tid & 63, wave = tid >> 6;
  const int wm = ((tid >> 7) & 3) * 64;
  const int wn = ((tid >> 6) & 1) * 64;

  #pragma unroll
  for (int m = 0; m < 4; ++m)
    #pragma unroll
    for (int n = 0; n < 4; ++n) acc[m][n] = (f32x4){0.f, 0.f, 0.f, 0.f};

  const int s_    = (lane & 7) ^ ((lane >> 3) & 7);
  const int srow2 = 2 * (lane >> 3) + (s_ >> 2);
  const int sk    = (s_ & 3) * 8;
  const u16* gsrc[3];
  int gdst[3];
  #pragma unroll
  for (int i = 0; i < 3; ++i) {
    int c = wave * 3 + i;
    if (c < 16) {
      gsrc[i] = A + (size_t)(m0 + c * 16 + srow2) * K + sk;
      gdst[i] = c * 512;
    } else {
      gsrc[i] = Wt + (size_t)(n0 + (c - 16) * 16 + srow2) * K + sk;
      gdst[i] = 8192 + (c - 16) * 512;
    }
  }

  int aoff[4], boff[4];
  #pragma unroll
  for (int m = 0; m < 4; ++m) {
    int r = wm + m * 16 + (lane & 15);
    int L = r >> 1;
    int phys = (((r & 1) << 2) + (lane >> 4)) ^ (L & 7);
    aoff[m] = L * 64 + phys * 8;
  }
  #pragma unroll
  for (int n = 0; n < 4; ++n) {
    int r = wn + n * 16 + (lane & 15);
    int L = r >> 1;
    int phys = (((r & 1) << 2) + (lane >> 4)) ^ (L & 7);
    boff[n] = 8192 + L * 64 + phys * 8;
  }

  #pragma unroll
  for (int j = 0; j < 2; ++j) {
    u16* sl = sm + j * 12288;
    #pragma unroll
    for (int i = 0; i < 3; ++i) gload16(gsrc[i] + j * 32, sl + gdst[i]);
  }
  asm volatile("s_waitcnt vmcnt(3)" ::: "memory");
  __builtin_amdgcn_s_barrier();

  int cs = 0;
  for (int j = 0; j < nt; ++j) {
    if (j + 2 < nt) {
      int ns = cs + 2; ns = (ns >= 3) ? ns - 3 : ns;
      u16* sl = sm + ns * 12288;
      #pragma unroll
      for (int i = 0; i < 3; ++i) gload16(gsrc[i] + (size_t)(j + 2) * 32, sl + gdst[i]);
    }
    const u16* sa = sm + cs * 12288;
    bf16x8 av[4], bv[4];
    #pragma unroll
    for (int m = 0; m < 4; ++m) av[m] = *(const bf16x8*)(sa + aoff[m]);
    #pragma unroll
    for (int n = 0; n < 4; ++n) bv[n] = *(const bf16x8*)(sa + boff[n]);
    __builtin_amdgcn_s_setprio(1);
    #pragma unroll
    for (int m = 0; m < 4; ++m)
      #pragma unroll
      for (int n = 0; n < 4; ++n)
        acc[m][n] = __builtin_amdgcn_mfma_f32_16x16x32_bf16(av[m], bv[n], acc[m][n], 0, 0, 0);
    __builtin_amdgcn_s_setprio(0);
    if (j + 2 < nt)      asm volatile("s_waitcnt vmcnt(3)" ::: "memory");
    else if (j + 1 < nt) asm volatile("s_waitcnt vmcnt(0)" ::: "memory");
    __builtin_amdgcn_s_barrier();
    cs = (cs == 2) ? 0 : cs + 1;
  }
}

// ---------------- stage kernels ----------------

// GEMM0SH: xb x WT0S[640,512]^T -> SH0E (cols<512, relu) + G0L (26 raw logits).
__global__ __launch_bounds__(512) void k_gemm0sh(const u16* __restrict__ xb,
    const u16* __restrict__ WT0S, const float* __restrict__ bias0s,
    u16* __restrict__ SH0E, float* __restrict__ G0L)
{
  __shared__ __align__(16) u16 sm[36864];
  f32x4 acc[4][4];
  const int bid = blockIdx.x;                 // 320 = 8 * 40
  const int swz = (bid & 7) * 40 + (bid >> 3);
  const int m0 = (swz / 5) * 256, n0 = (swz % 5) * 128;
  core32(xb, WT0S, 512, m0, n0, 16, sm, acc);
  const int lane = threadIdx.x & 63;
  const int wm = ((threadIdx.x >> 7) & 3) * 64, wn = ((threadIdx.x >> 6) & 1) * 64;
  #pragma unroll
  for (int mi = 0; mi < 4; ++mi)
    #pragma unroll
    for (int ni = 0; ni < 4; ++ni) {
      int gcol = n0 + wn + ni * 16 + (lane & 15);
      float bias = bias0s[gcol];
      #pragma unroll
      for (int q = 0; q < 4; ++q) {
        int grow = m0 + wm + mi * 16 + ((lane >> 4) << 2) + q;
        float v = acc[mi][ni][q] + bias;
        if (gcol < 512)      SH0E[(size_t)grow * 512 + gcol] = f2b(fmaxf(v, 0.f));
        else if (gcol < 538) G0L[(size_t)grow * 26 + (gcol - 512)] = v;
      }
    }
}

// SOFTG0: softmax the 26 gate-0 logits -> G0S[16384][32] (one row per thread).
__global__ __launch_bounds__(256) void k_softg0(const float* __restrict__ G0L,
    float* __restrict__ G0S)
{
  const int row = blockIdx.x * 256 + threadIdx.x;
  const float* l = G0L + (size_t)row * 26;
  float* o = G0S + (size_t)row * 32;
  #pragma unroll
  for (int t = 0; t < 4; ++t) {
    float l0 = l[t*4+0], l1 = l[t*4+1], l2 = l[t*4+2], l3 = l[t*4+3];
    float m = fmaxf(fmaxf(l0, l1), fmaxf(l2, l3));
    float e0 = expf(l0-m), e1 = expf(l1-m), e2 = expf(l2-m), e3 = expf(l3-m);
    float inv = 1.f / (e0 + e1 + e2 + e3);
    o[t*4+0] = e0*inv; o[t*4+1] = e1*inv; o[t*4+2] = e2*inv; o[t*4+3] = e3*inv;
  }
  float sg[10];
  float m = l[16];
  #pragma unroll
  for (int j = 1; j < 10; ++j) m = fmaxf(m, l[16+j]);
  float s = 0.f;
  #pragma unroll
  for (int j = 0; j < 10; ++j) { sg[j] = expf(l[16+j]-m); s += sg[j]; }
  float inv = 1.f / s;
  #pragma unroll
  for (int j = 0; j < 10; ++j) o[16+j] = sg[j] * inv;
}

// GEMM0T (R14-proven): task experts e-major (col = e*8 + te) + in-block mixing.
__global__ __launch_bounds__(512) void k_gemm0t(const u16* __restrict__ xb,
    const u16* __restrict__ WT0T, const float* __restrict__ bias0t,
    const u16* __restrict__ SH0E, const float* __restrict__ G0S,
    u16* __restrict__ T1SH)
{
  __shared__ __align__(16) u16 sm[36864];
  f32x4 acc[4][4];
  const int bid = blockIdx.x;                 // 1024 = 8 * 128
  const int swz = (bid & 7) * 128 + (bid >> 3);
  const int m0 = (swz >> 4) * 256, n0 = (swz & 15) * 128;
  core32(xb, WT0T, 512, m0, n0, 16, sm, acc);

  const int tid = threadIdx.x, lane = tid & 63;
  const int wmIdx = (tid >> 7) & 3;
  const int wn = ((tid >> 6) & 1) * 64;
  float* lds2 = (float*)sm;                   // 128 x 136 f32 = 69632 B
  const int ebase = n0 >> 3;

  for (int pair = 0; pair < 2; ++pair) {
    __syncthreads();
    #pragma unroll
    for (int mi2 = 0; mi2 < 2; ++mi2) {
      int mi = pair * 2 + mi2;
      #pragma unroll
      for (int ni = 0; ni < 4; ++ni) {
        int colL = wn + ni * 16 + (lane & 15);
        float bias = bias0t[n0 + colL];
        int el = colL >> 3, s2 = colL & 7;
        #pragma unroll
        for (int q = 0; q < 4; ++q) {
          int rl = wmIdx * 32 + mi2 * 16 + ((lane >> 4) << 2) + q;
          lds2[rl * 136 + el * 9 + s2] = fmaxf(acc[mi][ni][q] + bias, 0.f);
        }
      }
    }
    __syncthreads();
    const int r = tid >> 2, p = tid & 3;
    const int grow = m0 + (r >> 5) * 64 + pair * 32 + (r & 31);
    const float* gp = G0S + (size_t)grow * 32;
    u16x4 o[5];
    #pragma unroll
    for (int k = 0; k < 4; ++k) {
      int el = p * 4 + k;
      float ex[8];
      #pragma unroll
      for (int s2 = 0; s2 < 8; ++s2) ex[s2] = lds2[r * 136 + el * 9 + s2];
      int eg = ebase + el;
      float sh0v = b2f(SH0E[(size_t)grow * 512 + eg]);
      float sh1v = b2f(SH0E[(size_t)grow * 512 + 256 + eg]);
      float sha = gp[24] * sh0v + gp[25] * sh1v;
      #pragma unroll
      for (int t = 0; t < 4; ++t) {
        float v = gp[t*4+0] * ex[2*t] + gp[t*4+1] * ex[2*t+1]
                + gp[t*4+2] * sh0v    + gp[t*4+3] * sh1v;
        o[t][k] = f2b(v);
        sha += gp[16 + 2*t] * ex[2*t] + gp[17 + 2*t] * ex[2*t+1];
      }
      o[4][k] = f2b(sha);
    }
    int eg0 = ebase + p * 4;
    #pragma unroll
    for (int t = 0; t < 5; ++t)
      *(u16x4*)(T1SH + ((size_t)t * B_ + grow) * 256 + eg0) = o[t];
  }
}

// GATE1 (R14-proven): 16 level-1 gate logits per row from t1 -> G1S.
__global__ __launch_bounds__(256) void k_gate1(const u16* __restrict__ T1SH,
    const float* __restrict__ WG1T, const float* __restrict__ b_gate1,
    float* __restrict__ G1S)
{
  const int b = blockIdx.x * 8 + (threadIdx.x >> 5);
  const int e0 = (threadIdx.x & 31) * 8;
  float gp[16];
  #pragma unroll
  for (int t = 0; t < 4; ++t) {
    float v[8];
    ld8(T1SH + ((size_t)t * B_ + b) * 256 + e0, v);
    #pragma unroll
    for (int gg = 0; gg < 4; ++gg) {
      const float* wv = WG1T + ((size_t)(t * 4 + gg) * 256 + e0);
      float s = 0.f;
      #pragma unroll
      for (int j = 0; j < 8; ++j) s += v[j] * wv[j];
      gp[t * 4 + gg] = s;
    }
  }
  #pragma unroll
  for (int i = 0; i < 16; ++i) {
    #pragma unroll
    for (int off = 1; off < 32; off <<= 1)
      gp[i] += __shfl_xor(gp[i], off, 32);
  }
  if ((threadIdx.x & 31) == 0) {
    float* orow = G1S + (size_t)b * 16;
    #pragma unroll
    for (int z = 0; z < 4; ++z) {
      float l0 = gp[z*4+0] + b_gate1[z*4+0];
      float l1 = gp[z*4+1] + b_gate1[z*4+1];
      float l2 = gp[z*4+2] + b_gate1[z*4+2];
      float l3 = gp[z*4+3] + b_gate1[z*4+3];
      float m = fmaxf(fmaxf(l0, l1), fmaxf(l2, l3));
      float x0 = expf(l0-m), x1 = expf(l1-m), x2 = expf(l2-m), x3 = expf(l3-m);
      float inv = 1.f / (x0 + x1 + x2 + x3);
      orow[z*4+0] = x0*inv; orow[z*4+1] = x1*inv;
      orow[z*4+2] = x2*inv; orow[z*4+3] = x3*inv;
    }
  }
}

// GEMM1 (R10-proven): 20 panels (z 0..4 x 4 n-tiles of 128) x 64 m-blocks.
__global__ __launch_bounds__(512) void k_gemm1(const u16* __restrict__ T1SH,
    const u16* __restrict__ Wt1, const float* __restrict__ bias1,
    u16* __restrict__ E1, u16* __restrict__ SH1E)
{
  __shared__ __align__(16) u16 sm[36864];
  f32x4 acc[4][4];
  const int bid = blockIdx.x;                 // 1280 = 8 * 160
  const int swz = (bid & 7) * 160 + (bid >> 3);
  const int mi_ = swz / 20, pan = swz % 20;
  const int z  = pan >> 2;
  const int n0 = (pan & 3) * 128;
  const int m0 = mi_ * 256;
  core32(T1SH + (size_t)z * B_ * 256, Wt1 + (size_t)z * 512 * 256, 256, m0, n0, 8, sm, acc);
  const int lane = threadIdx.x & 63;
  const int wm = ((threadIdx.x >> 7) & 3) * 64, wn = ((threadIdx.x >> 6) & 1) * 64;
  const float* bias = bias1 + z * 512;
  #pragma unroll
  for (int mi = 0; mi < 4; ++mi)
    #pragma unroll
    for (int ni = 0; ni < 4; ++ni) {
      int gcol = n0 + wn + ni * 16 + (lane & 15);
      float bv = bias[gcol];
      #pragma unroll
      for (int q = 0; q < 4; ++q) {
        int grow = m0 + wm + mi * 16 + ((lane >> 4) << 2) + q;
        float v = fmaxf(acc[mi][ni][q] + bv, 0.f);
        if (z < 4) E1[((size_t)z * B_ + grow) * 512 + gcol] = f2b(v);
        else       SH1E[(size_t)grow * 512 + gcol] = f2b(v);
      }
    }
}

// TOWER2 (mix1 fused, R10-proven): A-tile = t2[z] built during reg-staging.
__global__ __launch_bounds__(256) void k_tower2(const u16* __restrict__ E1,
    const u16* __restrict__ SH1E, const float* __restrict__ G1S,
    const u16* __restrict__ Wtw, const float* __restrict__ b_tw,
    const float* __restrict__ w_out, const float* __restrict__ b_out,
    float* __restrict__ out)
{
  __shared__ __align__(16) u16 sm[32768];
  __shared__ float part[2][128][2];
  f32x4 acc[4][4];
  const int z = blockIdx.z;
  const int m0 = blockIdx.x * 128;
  const int tid = threadIdx.x, lane = tid & 63, wave = tid >> 6;
  const int wm = ((tid >> 7) & 1) * 64, wn = ((tid >> 6) & 1) * 64;

  #pragma unroll
  for (int mi = 0; mi < 4; ++mi)
    #pragma unroll
    for (int ni = 0; ni < 4; ++ni) acc[mi][ni] = (f32x4){0.f, 0.f, 0.f, 0.f};

  const int srow  = lane >> 3;
  const int gslot = (lane & 7) ^ srow;
  const int koff0 = gslot * 8;

  int growA[4], adst[4], bdst[4];
  const u16* bsrc[4];
  #pragma unroll
  for (int i = 0; i < 4; ++i) {
    int c = wave * 4 + i;
    growA[i] = m0 + c * 8 + srow;
    adst[i]  = c * 512;
    bsrc[i]  = Wtw + (size_t)z * 128 * 256 + (size_t)(c * 8 + srow) * 256 + koff0;
    bdst[i]  = 8192 + c * 512;
  }
  const u16* E1z = E1 + (size_t)z * B_ * 512;

  int aoff[2][4], boff[2][4];
  #pragma unroll
  for (int kk = 0; kk < 2; ++kk) {
    #pragma unroll
    for (int m = 0; m < 4; ++m) {
      int r = wm + m * 16 + (lane & 15);
      aoff[kk][m] = r * 64 + (((kk * 4 + (lane >> 4)) ^ (r & 7)) * 8);
    }
    #pragma unroll
    for (int n = 0; n < 4; ++n) {
      int r = wn + n * 16 + (lane & 15);
      boff[kk][n] = 8192 + r * 64 + (((kk * 4 + (lane >> 4)) ^ (r & 7)) * 8);
    }
  }

  #define STAGE_T(J, BUF) do {                                                 \
    u16* buf_ = (BUF);                                                         \
    _Pragma("unroll")                                                          \
    for (int i_ = 0; i_ < 4; ++i_) {                                           \
      size_t eoff_ = (size_t)growA[i_] * 512 + (J) * 64 + koff0;               \
      u16x8 ea_ = *(const u16x8*)(E1z + eoff_);                                \
      u16x8 eb_ = *(const u16x8*)(E1z + eoff_ + 256);                          \
      u16x8 sa_ = *(const u16x8*)(SH1E + eoff_);                               \
      u16x8 sb_ = *(const u16x8*)(SH1E + eoff_ + 256);                         \
      float4 g_ = *(const float4*)(G1S + (size_t)growA[i_] * 16 + z * 4);      \
      u16x8 o_;                                                                \
      _Pragma("unroll")                                                        \
      for (int jj_ = 0; jj_ < 8; ++jj_)                                        \
        o_[jj_] = f2b(g_.x * b2f(ea_[jj_]) + g_.y * b2f(eb_[jj_])              \
                    + g_.z * b2f(sa_[jj_]) + g_.w * b2f(sb_[jj_]));            \
      *(uint4*)(buf_ + adst[i_] + lane * 8) = __builtin_bit_cast(uint4, o_);   \
      gload16(bsrc[i_] + (J) * 64, buf_ + bdst[i_]);                           \
    }                                                                          \
  } while (0)

  STAGE_T(0, sm);
  __syncthreads();

  #pragma unroll
  for (int t = 0; t < 4; ++t) {
    if (t + 1 < 4) STAGE_T(t + 1, sm + ((t + 1) & 1) * 16384);
    const u16* sa = sm + (t & 1) * 16384;
    #pragma unroll
    for (int kk = 0; kk < 2; ++kk) {
      bf16x8 av[4], bv[4];
      #pragma unroll
      for (int m = 0; m < 4; ++m) av[m] = *(const bf16x8*)(sa + aoff[kk][m]);
      #pragma unroll
      for (int n = 0; n < 4; ++n) bv[n] = *(const bf16x8*)(sa + boff[kk][n]);
      #pragma unroll
      for (int m = 0; m < 4; ++m)
        #pragma unroll
        for (int n = 0; n < 4; ++n)
          acc[m][n] = __builtin_amdgcn_mfma_f32_16x16x32_bf16(av[m], bv[n], acc[m][n], 0, 0, 0);
    }
    if (t + 1 < 4) __syncthreads();
  }
  #undef STAGE_T

  #pragma unroll
  for (int mi = 0; mi < 4; ++mi) {
    #pragma unroll
    for (int r = 0; r < 4; ++r) {
      float p0 = 0.f, p1 = 0.f;
      #pragma unroll
      for (int ni = 0; ni < 4; ++ni) {
        int col = wn + ni * 16 + (lane & 15);
        float h = fmaxf(acc[mi][ni][r] + b_tw[z * 128 + col], 0.f);
        p0 += h * w_out[(z * 128 + col) * 2 + 0];
        p1 += h * w_out[(z * 128 + col) * 2 + 1];
      }
      #pragma unroll
      for (int off = 1; off < 16; off <<= 1) {
        p0 += __shfl_xor(p0, off);
        p1 += __shfl_xor(p1, off);
      }
      if ((lane & 15) == 0) {
        int rowl = wm + mi * 16 + ((lane >> 4) << 2) + r;
        part[wn >> 6][rowl][0] = p0;
        part[wn >> 6][rowl][1] = p1;
      }
    }
  }
  __syncthreads();
  if (threadIdx.x < 128) {
    int rowl = threadIdx.x;
    float l0 = part[0][rowl][0] + part[1][rowl][0] + b_out[z * 2 + 0];
    float l1 = part[0][rowl][1] + part[1][rowl][1] + b_out[z * 2 + 1];
    float mx = fmaxf(l0, l1);
    float e0 = expf(l0 - mx), e1 = expf(l1 - mx);
    float inv = 1.f / (e0 + e1);
    float p0 = fminf(fmaxf(e0 * inv, 1e-15f), 1.0f);
    float p1 = fminf(fmaxf(e1 * inv, 1e-15f), 1.0f);
    size_t o = ((size_t)z * B_ + m0 + rowl) * 2;
    out[o] = p0; out[o + 1] = p1;
  }
}

// PREP: cast x; e-major task panel WT0T; WT0S[640] (shared + gate0 cols);
// WT1, WTW, WG1T + bias vectors.
__global__ void k_prep(const float* __restrict__ x,
    const float* __restrict__ w_task0, const float* __restrict__ b_task0,
    const float* __restrict__ w_sh0,   const float* __restrict__ b_sh0,
    const float* __restrict__ w_gate0, const float* __restrict__ b_gate0,
    const float* __restrict__ w_gsh0,  const float* __restrict__ b_gsh0,
    const float* __restrict__ w_task1, const float* __restrict__ b_task1,
    const float* __restrict__ w_sh1,   const float* __restrict__ b_sh1,
    const float* __restrict__ w_gate1, const float* __restrict__ w_tw,
    u16* __restrict__ xb, u16* __restrict__ WT0T, float* __restrict__ bias0t,
    u16* __restrict__ WT0S, float* __restrict__ bias0s,
    u16* __restrict__ Wt1, float* __restrict__ bias1,
    u16* __restrict__ Wtw, float* __restrict__ WG1T)
{
  size_t i = (size_t)blockIdx.x * 256 + threadIdx.x;
  const size_t S_X8  = (size_t)16384 * 512 / 8; // 1048576
  const size_t S_T   = (size_t)2048 * 512;      // 1048576
  const size_t S_BT  = 2048;
  const size_t S_S   = (size_t)640 * 512;       // 327680
  const size_t S_BS  = 640;
  const size_t S_WT1 = (size_t)5 * 512 * 256;   // 655360
  const size_t S_B1  = 5 * 512;                 // 2560
  const size_t S_WTW = (size_t)4 * 128 * 256;   // 131072
  const size_t S_WG1 = 4096;

  if (i < S_X8) {
    size_t o = i * 8;
    float4 a = *(const float4*)(x + o);
    float4 b = *(const float4*)(x + o + 4);
    u16x8 v;
    v[0] = f2b(a.x); v[1] = f2b(a.y); v[2] = f2b(a.z); v[3] = f2b(a.w);
    v[4] = f2b(b.x); v[5] = f2b(b.y); v[6] = f2b(b.z); v[7] = f2b(b.w);
    *(u16x8*)(xb + o) = v;
    return;
  }
  i -= S_X8;
  if (i < S_T) {       // e-major task experts: col c = e*8 + te
    int c = (int)(i / 512), f = (int)(i % 512);
    int te = c & 7, e = c >> 3;
    WT0T[i] = f2b(w_task0[((size_t)te * 512 + f) * 256 + e]);
    return;
  }
  i -= S_T;
  if (i < S_BT) {
    int te = (int)i & 7, e = (int)i >> 3;
    bias0t[i] = b_task0[te * 256 + e];
    return;
  }
  i -= S_BT;
  if (i < S_S) {       // shared experts + gate0 cols (512..537), pad to 640
    int c = (int)(i / 512), f = (int)(i % 512);
    float v = 0.f;
    if (c < 512)      { int s = c >> 8, e = c & 255; v = w_sh0[((size_t)s * 512 + f) * 256 + e]; }
    else if (c < 528) { int q = c - 512; int t = q >> 2, gg = q & 3; v = w_gate0[((size_t)t * 512 + f) * 4 + gg]; }
    else if (c < 538) { v = w_gsh0[(size_t)f * 10 + (c - 528)]; }
    WT0S[i] = f2b(v);
    return;
  }
  i -= S_S;
  if (i < S_BS) {
    int c = (int)i; float v = 0.f;
    if (c < 512)      { int s = c >> 8, e = c & 255; v = b_sh0[s * 256 + e]; }
    else if (c < 528) { v = b_gate0[c - 512]; }
    else if (c < 538) { v = b_gsh0[c - 528]; }
    bias0s[c] = v;
    return;
  }
  i -= S_BS;
  if (i < S_WT1) {
    int z = (int)(i / (512 * 256)); int rem = (int)(i % (512 * 256));
    int c = rem / 256, f = rem % 256;
    float v;
    if (z < 4) { int ee = c >> 8, o = c & 255; v = w_task1[(((size_t)(z * 2 + ee)) * 256 + f) * 256 + o]; }
    else       { int s = c >> 8, o = c & 255; v = w_sh1[((size_t)s * 256 + f) * 256 + o]; }
    Wt1[i] = f2b(v);
    return;
  }
  i -= S_WT1;
  if (i < S_B1) {
    int z = (int)(i / 512); int c = (int)(i % 512);
    float v;
    if (z < 4) { int ee = c >> 8, o = c & 255; v = b_task1[(z * 2 + ee) * 256 + o]; }
    else       { int s = c >> 8, o = c & 255; v = b_sh1[s * 256 + o]; }
    bias1[(size_t)z * 512 + c] = v;
    return;
  }
  i -= S_B1;
  if (i < S_WTW) {
    int z = (int)(i / (128 * 256)); int rem = (int)(i % (128 * 256));
    int h = rem / 256, f = rem % 256;
    Wtw[i] = f2b(w_tw[((size_t)z * 256 + f) * 128 + h]);
    return;
  }
  i -= S_WTW;
  if (i < S_WG1) {
    int t = (int)(i >> 10), gg = (int)((i >> 8) & 3), e = (int)(i & 255);
    WG1T[i] = w_gate1[((size_t)t * 256 + e) * 4 + gg];
    return;
  }
}

extern "C" void kernel_launch(void* const* d_in, const int* in_sizes, int n_in,
                              void* d_out, int out_size, void* d_ws, size_t ws_size,
                              hipStream_t stream)
{
  (void)in_sizes; (void)n_in; (void)out_size; (void)ws_size;
  const float* x       = (const float*)d_in[0];
  const float* w_task0 = (const float*)d_in[1];
  const float* b_task0 = (const float*)d_in[2];
  const float* w_sh0   = (const float*)d_in[3];
  const float* b_sh0   = (const float*)d_in[4];
  const float* w_gate0 = (const float*)d_in[5];
  const float* b_gate0 = (const float*)d_in[6];
  const float* w_gsh0  = (const float*)d_in[7];
  const float* b_gsh0  = (const float*)d_in[8];
  const float* w_task1 = (const float*)d_in[9];
  const float* b_task1 = (const float*)d_in[10];
  const float* w_sh1   = (const float*)d_in[11];
  const float* b_sh1   = (const float*)d_in[12];
  const float* w_gate1 = (const float*)d_in[13];
  const float* b_gate1 = (const float*)d_in[14];
  const float* w_tw    = (const float*)d_in[15];
  const float* b_tw    = (const float*)d_in[16];
  const float* w_out   = (const float*)d_in[17];
  const float* b_out   = (const float*)d_in[18];
  float* out = (float*)d_out;

  char* ws = (char*)d_ws;
  u16*   XB    = (u16*)  (ws + 0);            //  16,777,216  [16384][512]
  u16*   SH1E  = (u16*)  (ws + 0);            //  reuses XB (first write: gemm1)
  u16*   WT0T  = (u16*)  (ws + 16777216);     //   2,097,152  [2048][512] e-major
  float* BIAS0T= (float*)(ws + 18874368);     //       8,192  [2048]
  u16*   WT0S  = (u16*)  (ws + 18882560);     //     655,360  [640][512]
  float* BIAS0S= (float*)(ws + 19537920);     //       2,560  [640]
  u16*   WT1   = (u16*)  (ws + 19540480);     //   1,310,720  [5][512][256]
  float* BIAS1 = (float*)(ws + 20851200);     //      10,240  [5][512]
  u16*   WTW   = (u16*)  (ws + 20861440);     //     262,144  [4][128][256]
  float* WG1T  = (float*)(ws + 21123584);     //      16,384  [4][4][256]
  u16*   SH0E  = (u16*)  (ws + 21139968);     //  16,777,216  [16384][512]
  float* G0L   = (float*)(ws + 37917184);     //   1,703,936  [16384][26]
  float* G0S   = (float*)(ws + 39621120);     //   2,097,152  [16384][32]
  u16*   T1SH  = (u16*)  (ws + 41718272);     //  41,943,040  [5][16384][256]
  u16*   E1    = (u16*)  (ws + 83661312);     //  67,108,864  [4][16384][512]
  float* G1S   = (float*)(ws + 150770176);    //   1,048,576  [16384][16]

  k_prep<<<12581, 256, 0, stream>>>(x, w_task0, b_task0, w_sh0, b_sh0,
      w_gate0, b_gate0, w_gsh0, b_gsh0, w_task1, b_task1, w_sh1, b_sh1,
      w_gate1, w_tw,
      XB, WT0T, BIAS0T, WT0S, BIAS0S, WT1, BIAS1, WTW, WG1T);
  k_gemm0sh<<<320, 512, 0, stream>>>(XB, WT0S, BIAS0S, SH0E, G0L);
  k_softg0<<<64, 256, 0, stream>>>(G0L, G0S);
  k_gemm0t<<<1024, 512, 0, stream>>>(XB, WT0T, BIAS0T, SH0E, G0S, T1SH);
  k_gate1<<<2048, 256, 0, stream>>>(T1SH, WG1T, b_gate1, G1S);
  k_gemm1<<<1280, 512, 0, stream>>>(T1SH, WT1, BIAS1, E1, SH1E);
  k_tower2<<<dim3(128, 1, 4), 256, 0, stream>>>(E1, SH1E, G1S, WTW, b_tw, w_out, b_out, out);
}

// Round 16
// 176.381 us; speedup vs baseline: 1.4088x; 1.0013x over previous
//
#include <hip/hip_runtime.h>

typedef unsigned short u16;
typedef __bf16 bf16x8 __attribute__((ext_vector_type(8)));
typedef float f32x4 __attribute__((ext_vector_type(4)));
typedef u16 u16x8 __attribute__((ext_vector_type(8)));
typedef u16 u16x2 __attribute__((ext_vector_type(2)));

#define B_ 16384

__device__ __forceinline__ u16 f2b(float f){
  unsigned u = __builtin_bit_cast(unsigned, f);
  u = (u + 0x7FFFu + ((u >> 16) & 1u)) >> 16;   // RNE
  return (u16)u;
}
__device__ __forceinline__ float b2f(u16 v){
  return __builtin_bit_cast(float, ((unsigned)v) << 16);
}
__device__ __forceinline__ void ld8(const u16* __restrict__ p, float* f){
  u16x8 v = *(const u16x8*)p;
  #pragma unroll
  for (int j = 0; j < 8; ++j) f[j] = b2f(v[j]);
}

__device__ __forceinline__ void gload16(const u16* g, u16* lds){
  __builtin_amdgcn_global_load_lds(
      (const __attribute__((address_space(1))) unsigned int*)g,
      (__attribute__((address_space(3))) unsigned int*)lds, 16, 0, 0);
}

// ===== core32 (R9/R10-proven): BM=256, BN=128, BK=32, ring-3, counted vmcnt =
__device__ __forceinline__ void core32(const u16* __restrict__ A,
                                       const u16* __restrict__ Wt,
                                       int K, int m0, int n0, int nt,
                                       u16* sm, f32x4 acc[4][4])
{
  const int tid = threadIdx.x, lane = tid & 63, wave = tid >> 6;
  const int wm = ((tid >> 7) & 3) * 64;
  const int wn = ((tid >> 6) & 1) * 64;

  #pragma unroll
  for (int m = 0; m < 4; ++m)
    #pragma unroll
    for (int n = 0; n < 4; ++n) acc[m][n] = (f32x4){0.f, 0.f, 0.f, 0.f};

  const int s_    = (lane & 7) ^ ((lane >> 3) & 7);
  const int srow2 = 2 * (lane >> 3) + (s_ >> 2);
  const int sk    = (s_ & 3) * 8;
  const u16* gsrc[3];
  int gdst[3];
  #pragma unroll
  for (int i = 0; i < 3; ++i) {
    int c = wave * 3 + i;
    if (c < 16) {
      gsrc[i] = A + (size_t)(m0 + c * 16 + srow2) * K + sk;
      gdst[i] = c * 512;
    } else {
      gsrc[i] = Wt + (size_t)(n0 + (c - 16) * 16 + srow2) * K + sk;
      gdst[i] = 8192 + (c - 16) * 512;
    }
  }

  int aoff[4], boff[4];
  #pragma unroll
  for (int m = 0; m < 4; ++m) {
    int r = wm + m * 16 + (lane & 15);
    int L = r >> 1;
    int phys = (((r & 1) << 2) + (lane >> 4)) ^ (L & 7);
    aoff[m] = L * 64 + phys * 8;
  }
  #pragma unroll
  for (int n = 0; n < 4; ++n) {
    int r = wn + n * 16 + (lane & 15);
    int L = r >> 1;
    int phys = (((r & 1) << 2) + (lane >> 4)) ^ (L & 7);
    boff[n] = 8192 + L * 64 + phys * 8;
  }

  #pragma unroll
  for (int j = 0; j < 2; ++j) {
    u16* sl = sm + j * 12288;
    #pragma unroll
    for (int i = 0; i < 3; ++i) gload16(gsrc[i] + j * 32, sl + gdst[i]);
  }
  asm volatile("s_waitcnt vmcnt(3)" ::: "memory");
  __builtin_amdgcn_s_barrier();

  int cs = 0;
  for (int j = 0; j < nt; ++j) {
    if (j + 2 < nt) {
      int ns = cs + 2; ns = (ns >= 3) ? ns - 3 : ns;
      u16* sl = sm + ns * 12288;
      #pragma unroll
      for (int i = 0; i < 3; ++i) gload16(gsrc[i] + (size_t)(j + 2) * 32, sl + gdst[i]);
    }
    const u16* sa = sm + cs * 12288;
    bf16x8 av[4], bv[4];
    #pragma unroll
    for (int m = 0; m < 4; ++m) av[m] = *(const bf16x8*)(sa + aoff[m]);
    #pragma unroll
    for (int n = 0; n < 4; ++n) bv[n] = *(const bf16x8*)(sa + boff[n]);
    __builtin_amdgcn_s_setprio(1);
    #pragma unroll
    for (int m = 0; m < 4; ++m)
      #pragma unroll
      for (int n = 0; n < 4; ++n)
        acc[m][n] = __builtin_amdgcn_mfma_f32_16x16x32_bf16(av[m], bv[n], acc[m][n], 0, 0, 0);
    __builtin_amdgcn_s_setprio(0);
    if (j + 2 < nt)      asm volatile("s_waitcnt vmcnt(3)" ::: "memory");
    else if (j + 1 < nt) asm volatile("s_waitcnt vmcnt(0)" ::: "memory");
    __builtin_amdgcn_s_barrier();
    cs = (cs == 2) ? 0 : cs + 1;
  }
}

// ====== GEMM0U: unified level-0. BM=128, B-panel 192 rows (128 task e-major,
// 32 shared for SAME e's, 32 gate cols replicated), 8 waves 2M x 4N,
// acc[4][3] (~110 VGPR). Ring-3 24KB slots (B padded to 256 rows -> 24 chunks
// = 3/wave, uniform vmcnt(3)). Epilogue: acc->LDS (odd strides), per-row
// softmax of block-local 26 gate logits, mix, write T1SH. No SH0E/G0S/E0.
__global__ __launch_bounds__(512) void k_gemm0u(const u16* __restrict__ xb,
    const u16* __restrict__ WT0T, const float* __restrict__ bias0t,
    const u16* __restrict__ WT0SH, const float* __restrict__ bias0sh,
    const u16* __restrict__ WT0G, const float* __restrict__ bias0g,
    u16* __restrict__ T1SH)
{
  __shared__ __align__(16) u16 sm[36864];   // 72KB: ring 3 x 12288 u16
  const int tid = threadIdx.x, lane = tid & 63, wave = tid >> 6;
  const int wm = (wave >> 2) * 64;          // 2 M-waves
  const int nw = wave & 3;                  // 4 N-waves x 48 cols

  const int bid = blockIdx.x;               // 2048 = 8 * 256
  const int swz = (bid & 7) * 256 + (bid >> 3);
  const int mt = swz >> 4, ep = swz & 15;   // ep fastest: A m-tile L2-hot
  const int m0 = mt * 128;

  f32x4 acc[4][3];
  #pragma unroll
  for (int m = 0; m < 4; ++m)
    #pragma unroll
    for (int n = 0; n < 3; ++n) acc[m][n] = (f32x4){0.f, 0.f, 0.f, 0.f};

  // ---- staging: 24 chunks (A:0..7, B:8..23; B rows 192..255 = pad) ----
  const int s_    = (lane & 7) ^ ((lane >> 3) & 7);
  const int srow2 = 2 * (lane >> 3) + (s_ >> 2);
  const int sk    = (s_ & 3) * 8;
  const u16* gsrc[3];
  int gdst[3];
  #pragma unroll
  for (int i = 0; i < 3; ++i) {
    int c = wave * 3 + i;
    const u16* src;
    if (c < 8) {
      src = xb + (size_t)(m0 + c * 16 + srow2) * 512 + sk;
      gdst[i] = c * 512;
    } else {
      int rb16 = c - 8;                    // 16-row group of B
      if (rb16 < 8)        src = WT0T  + (size_t)(ep * 128 + rb16 * 16 + srow2) * 512 + sk;
      else if (rb16 == 8)  src = WT0SH + (size_t)(ep * 16 + srow2) * 512 + sk;
      else if (rb16 == 9)  src = WT0SH + (size_t)(256 + ep * 16 + srow2) * 512 + sk;
      else if (rb16 < 12)  src = WT0G  + (size_t)((rb16 - 10) * 16 + srow2) * 512 + sk;
      else                 src = WT0G  + (size_t)srow2 * 512 + sk;   // pad
      gdst[i] = 4096 + rb16 * 512;
    }
    gsrc[i] = src;
  }

  // ---- ds-read offsets ----
  int aoff[4], boff[3];
  #pragma unroll
  for (int m = 0; m < 4; ++m) {
    int r = wm + m * 16 + (lane & 15);
    int L = r >> 1;
    int phys = (((r & 1) << 2) + (lane >> 4)) ^ (L & 7);
    aoff[m] = L * 64 + phys * 8;
  }
  #pragma unroll
  for (int n = 0; n < 3; ++n) {
    int rb = nw * 48 + n * 16 + (lane & 15);
    int L = rb >> 1;
    int phys = (((rb & 1) << 2) + (lane >> 4)) ^ (L & 7);
    boff[n] = 4096 + L * 64 + phys * 8;
  }

  // prologue: stage steps 0,1
  #pragma unroll
  for (int j = 0; j < 2; ++j) {
    u16* sl = sm + j * 12288;
    #pragma unroll
    for (int i = 0; i < 3; ++i) gload16(gsrc[i] + j * 32, sl + gdst[i]);
  }
  asm volatile("s_waitcnt vmcnt(3)" ::: "memory");
  __builtin_amdgcn_s_barrier();

  int cs = 0;
  for (int j = 0; j < 16; ++j) {
    if (j + 2 < 16) {
      int ns = cs + 2; ns = (ns >= 3) ? ns - 3 : ns;
      u16* sl = sm + ns * 12288;
      #pragma unroll
      for (int i = 0; i < 3; ++i) gload16(gsrc[i] + (size_t)(j + 2) * 32, sl + gdst[i]);
    }
    const u16* sa = sm + cs * 12288;
    bf16x8 av[4], bv[3];
    #pragma unroll
    for (int m = 0; m < 4; ++m) av[m] = *(const bf16x8*)(sa + aoff[m]);
    #pragma unroll
    for (int n = 0; n < 3; ++n) bv[n] = *(const bf16x8*)(sa + boff[n]);
    __builtin_amdgcn_s_setprio(1);
    #pragma unroll
    for (int m = 0; m < 4; ++m)
      #pragma unroll
      for (int n = 0; n < 3; ++n)
        acc[m][n] = __builtin_amdgcn_mfma_f32_16x16x32_bf16(av[m], bv[n], acc[m][n], 0, 0, 0);
    __builtin_amdgcn_s_setprio(0);
    if (j + 2 < 16)      asm volatile("s_waitcnt vmcnt(3)" ::: "memory");
    else if (j + 1 < 16) asm volatile("s_waitcnt vmcnt(0)" ::: "memory");
    __builtin_amdgcn_s_barrier();
    cs = (cs == 2) ? 0 : cs + 1;
  }

  // ---- epilogue: 2 halves of 64 rows ----
  float* t_lds = (float*)sm;               // [64][129]  task (relu)
  float* s_lds = t_lds + 8256;             // [64][33]   shared (relu)
  float* g_lds = t_lds + 8256 + 2112;      // [64][33]   gate logits -> probs

  for (int pair = 0; pair < 2; ++pair) {
    __syncthreads();
    // phase A: acc -> LDS (+bias, relu for experts)
    #pragma unroll
    for (int mi2 = 0; mi2 < 2; ++mi2) {
      int mi = pair * 2 + mi2;
      #pragma unroll
      for (int ni = 0; ni < 3; ++ni) {
        int c = nw * 48 + ni * 16 + (lane & 15);
        float bias;
        if (c < 128)      bias = bias0t[ep * 128 + c];
        else if (c < 160) { int idx = c - 128; bias = bias0sh[(idx >> 4) * 256 + ep * 16 + (idx & 15)]; }
        else              bias = bias0g[c - 160];
        #pragma unroll
        for (int q = 0; q < 4; ++q) {
          int lr = (wm >> 1) + mi2 * 16 + ((lane >> 4) << 2) + q;
          float v = acc[mi][ni][q] + bias;
          if (c < 128)      t_lds[lr * 129 + c] = fmaxf(v, 0.f);
          else if (c < 160) s_lds[lr * 33 + (c - 128)] = fmaxf(v, 0.f);
          else              g_lds[lr * 33 + (c - 160)] = v;
        }
      }
    }
    __syncthreads();
    // softmax: one thread per row
    if (tid < 64) {
      float* gl = g_lds + tid * 33;
      #pragma unroll
      for (int t = 0; t < 4; ++t) {
        float l0 = gl[t*4+0], l1 = gl[t*4+1], l2 = gl[t*4+2], l3 = gl[t*4+3];
        float m = fmaxf(fmaxf(l0, l1), fmaxf(l2, l3));
        float e0 = expf(l0-m), e1 = expf(l1-m), e2 = expf(l2-m), e3 = expf(l3-m);
        float inv = 1.f / (e0 + e1 + e2 + e3);
        gl[t*4+0] = e0*inv; gl[t*4+1] = e1*inv; gl[t*4+2] = e2*inv; gl[t*4+3] = e3*inv;
      }
      float sg[10];
      float m = gl[16];
      #pragma unroll
      for (int j = 1; j < 10; ++j) m = fmaxf(m, gl[16+j]);
      float s = 0.f;
      #pragma unroll
      for (int j = 0; j < 10; ++j) { sg[j] = expf(gl[16+j]-m); s += sg[j]; }
      float inv = 1.f / s;
      #pragma unroll
      for (int j = 0; j < 10; ++j) gl[16+j] = sg[j] * inv;
    }
    __syncthreads();
    // mix: thread (lr = tid>>3, h = tid&7) handles k = 2h, 2h+1
    {
      const int lr = tid >> 3, h = tid & 7;
      const int grow = m0 + ((lr < 32) ? (pair * 32 + lr) : (64 + pair * 32 + (lr - 32)));
      const float* gl = g_lds + lr * 33;
      u16x2 o[5];
      #pragma unroll
      for (int d = 0; d < 2; ++d) {
        int k = h * 2 + d;
        float ex[8];
        #pragma unroll
        for (int te = 0; te < 8; ++te) ex[te] = t_lds[lr * 129 + k * 8 + te];
        float sh0 = s_lds[lr * 33 + k];
        float sh1 = s_lds[lr * 33 + 16 + k];
        float sha = gl[24] * sh0 + gl[25] * sh1;
        #pragma unroll
        for (int t = 0; t < 4; ++t) {
          float v = gl[t*4+0] * ex[2*t] + gl[t*4+1] * ex[2*t+1]
                  + gl[t*4+2] * sh0     + gl[t*4+3] * sh1;
          o[t][d] = f2b(v);
          sha += gl[16 + 2*t] * ex[2*t] + gl[17 + 2*t] * ex[2*t+1];
        }
        o[4][d] = f2b(sha);
      }
      #pragma unroll
      for (int t = 0; t < 5; ++t)
        *(u16x2*)(T1SH + ((size_t)t * B_ + grow) * 256 + ep * 16 + h * 2) = o[t];
    }
  }
}

// GATE1 (R14-proven): 16 level-1 gate logits per row from t1 -> G1S.
__global__ __launch_bounds__(256) void k_gate1(const u16* __restrict__ T1SH,
    const float* __restrict__ WG1T, const float* __restrict__ b_gate1,
    float* __restrict__ G1S)
{
  const int b = blockIdx.x * 8 + (threadIdx.x >> 5);
  const int e0 = (threadIdx.x & 31) * 8;
  float gp[16];
  #pragma unroll
  for (int t = 0; t < 4; ++t) {
    float v[8];
    ld8(T1SH + ((size_t)t * B_ + b) * 256 + e0, v);
    #pragma unroll
    for (int gg = 0; gg < 4; ++gg) {
      const float* wv = WG1T + ((size_t)(t * 4 + gg) * 256 + e0);
      float s = 0.f;
      #pragma unroll
      for (int j = 0; j < 8; ++j) s += v[j] * wv[j];
      gp[t * 4 + gg] = s;
    }
  }
  #pragma unroll
  for (int i = 0; i < 16; ++i) {
    #pragma unroll
    for (int off = 1; off < 32; off <<= 1)
      gp[i] += __shfl_xor(gp[i], off, 32);
  }
  if ((threadIdx.x & 31) == 0) {
    float* orow = G1S + (size_t)b * 16;
    #pragma unroll
    for (int z = 0; z < 4; ++z) {
      float l0 = gp[z*4+0] + b_gate1[z*4+0];
      float l1 = gp[z*4+1] + b_gate1[z*4+1];
      float l2 = gp[z*4+2] + b_gate1[z*4+2];
      float l3 = gp[z*4+3] + b_gate1[z*4+3];
      float m = fmaxf(fmaxf(l0, l1), fmaxf(l2, l3));
      float x0 = expf(l0-m), x1 = expf(l1-m), x2 = expf(l2-m), x3 = expf(l3-m);
      float inv = 1.f / (x0 + x1 + x2 + x3);
      orow[z*4+0] = x0*inv; orow[z*4+1] = x1*inv;
      orow[z*4+2] = x2*inv; orow[z*4+3] = x3*inv;
    }
  }
}

// GEMM1 (R10-proven): 20 panels (z 0..4 x 4 n-tiles of 128) x 64 m-blocks.
__global__ __launch_bounds__(512) void k_gemm1(const u16* __restrict__ T1SH,
    const u16* __restrict__ Wt1, const float* __restrict__ bias1,
    u16* __restrict__ E1, u16* __restrict__ SH1E)
{
  __shared__ __align__(16) u16 sm[36864];
  f32x4 acc[4][4];
  const int bid = blockIdx.x;                 // 1280 = 8 * 160
  const int swz = (bid & 7) * 160 + (bid >> 3);
  const int mi_ = swz / 20, pan = swz % 20;
  const int z  = pan >> 2;
  const int n0 = (pan & 3) * 128;
  const int m0 = mi_ * 256;
  core32(T1SH + (size_t)z * B_ * 256, Wt1 + (size_t)z * 512 * 256, 256, m0, n0, 8, sm, acc);
  const int lane = threadIdx.x & 63;
  const int wm = ((threadIdx.x >> 7) & 3) * 64, wn = ((threadIdx.x >> 6) & 1) * 64;
  const float* bias = bias1 + z * 512;
  #pragma unroll
  for (int mi = 0; mi < 4; ++mi)
    #pragma unroll
    for (int ni = 0; ni < 4; ++ni) {
      int gcol = n0 + wn + ni * 16 + (lane & 15);
      float bv = bias[gcol];
      #pragma unroll
      for (int q = 0; q < 4; ++q) {
        int grow = m0 + wm + mi * 16 + ((lane >> 4) << 2) + q;
        float v = fmaxf(acc[mi][ni][q] + bv, 0.f);
        if (z < 4) E1[((size_t)z * B_ + grow) * 512 + gcol] = f2b(v);
        else       SH1E[(size_t)grow * 512 + gcol] = f2b(v);
      }
    }
}

// TOWER2 (mix1 fused, R10-proven): A-tile = t2[z] built during reg-staging.
__global__ __launch_bounds__(256) void k_tower2(const u16* __restrict__ E1,
    const u16* __restrict__ SH1E, const float* __restrict__ G1S,
    const u16* __restrict__ Wtw, const float* __restrict__ b_tw,
    const float* __restrict__ w_out, const float* __restrict__ b_out,
    float* __restrict__ out)
{
  __shared__ __align__(16) u16 sm[32768];
  __shared__ float part[2][128][2];
  f32x4 acc[4][4];
  const int z = blockIdx.z;
  const int m0 = blockIdx.x * 128;
  const int tid = threadIdx.x, lane = tid & 63, wave = tid >> 6;
  const int wm = ((tid >> 7) & 1) * 64, wn = ((tid >> 6) & 1) * 64;

  #pragma unroll
  for (int mi = 0; mi < 4; ++mi)
    #pragma unroll
    for (int ni = 0; ni < 4; ++ni) acc[mi][ni] = (f32x4){0.f, 0.f, 0.f, 0.f};

  const int srow  = lane >> 3;
  const int gslot = (lane & 7) ^ srow;
  const int koff0 = gslot * 8;

  int growA[4], adst[4], bdst[4];
  const u16* bsrc[4];
  #pragma unroll
  for (int i = 0; i < 4; ++i) {
    int c = wave * 4 + i;
    growA[i] = m0 + c * 8 + srow;
    adst[i]  = c * 512;
    bsrc[i]  = Wtw + (size_t)z * 128 * 256 + (size_t)(c * 8 + srow) * 256 + koff0;
    bdst[i]  = 8192 + c * 512;
  }
  const u16* E1z = E1 + (size_t)z * B_ * 512;

  int aoff[2][4], boff[2][4];
  #pragma unroll
  for (int kk = 0; kk < 2; ++kk) {
    #pragma unroll
    for (int m = 0; m < 4; ++m) {
      int r = wm + m * 16 + (lane & 15);
      aoff[kk][m] = r * 64 + (((kk * 4 + (lane >> 4)) ^ (r & 7)) * 8);
    }
    #pragma unroll
    for (int n = 0; n < 4; ++n) {
      int r = wn + n * 16 + (lane & 15);
      boff[kk][n] = 8192 + r * 64 + (((kk * 4 + (lane >> 4)) ^ (r & 7)) * 8);
    }
  }

  #define STAGE_T(J, BUF) do {                                                 \
    u16* buf_ = (BUF);                                                         \
    _Pragma("unroll")                                                          \
    for (int i_ = 0; i_ < 4; ++i_) {                                           \
      size_t eoff_ = (size_t)growA[i_] * 512 + (J) * 64 + koff0;               \
      u16x8 ea_ = *(const u16x8*)(E1z + eoff_);                                \
      u16x8 eb_ = *(const u16x8*)(E1z + eoff_ + 256);                          \
      u16x8 sa_ = *(const u16x8*)(SH1E + eoff_);                               \
      u16x8 sb_ = *(const u16x8*)(SH1E + eoff_ + 256);                         \
      float4 g_ = *(const float4*)(G1S + (size_t)growA[i_] * 16 + z * 4);      \
      u16x8 o_;                                                                \
      _Pragma("unroll")                                                        \
      for (int jj_ = 0; jj_ < 8; ++jj_)                                        \
        o_[jj_] = f2b(g_.x * b2f(ea_[jj_]) + g_.y * b2f(eb_[jj_])              \
                    + g_.z * b2f(sa_[jj_]) + g_.w * b2f(sb_[jj_]));            \
      *(uint4*)(buf_ + adst[i_] + lane * 8) = __builtin_bit_cast(uint4, o_);   \
      gload16(bsrc[i_] + (J) * 64, buf_ + bdst[i_]);                           \
    }                                                                          \
  } while (0)

  STAGE_T(0, sm);
  __syncthreads();

  #pragma unroll
  for (int t = 0; t < 4; ++t) {
    if (t + 1 < 4) STAGE_T(t + 1, sm + ((t + 1) & 1) * 16384);
    const u16* sa = sm + (t & 1) * 16384;
    #pragma unroll
    for (int kk = 0; kk < 2; ++kk) {
      bf16x8 av[4], bv[4];
      #pragma unroll
      for (int m = 0; m < 4; ++m) av[m] = *(const bf16x8*)(sa + aoff[kk][m]);
      #pragma unroll
      for (int n = 0; n < 4; ++n) bv[n] = *(const bf16x8*)(sa + boff[kk][n]);
      #pragma unroll
      for (int m = 0; m < 4; ++m)
        #pragma unroll
        for (int n = 0; n < 4; ++n)
          acc[m][n] = __builtin_amdgcn_mfma_f32_16x16x32_bf16(av[m], bv[n], acc[m][n], 0, 0, 0);
    }
    if (t + 1 < 4) __syncthreads();
  }
  #undef STAGE_T

  #pragma unroll
  for (int mi = 0; mi < 4; ++mi) {
    #pragma unroll
    for (int r = 0; r < 4; ++r) {
      float p0 = 0.f, p1 = 0.f;
      #pragma unroll
      for (int ni = 0; ni < 4; ++ni) {
        int col = wn + ni * 16 + (lane & 15);
        float h = fmaxf(acc[mi][ni][r] + b_tw[z * 128 + col], 0.f);
        p0 += h * w_out[(z * 128 + col) * 2 + 0];
        p1 += h * w_out[(z * 128 + col) * 2 + 1];
      }
      #pragma unroll
      for (int off = 1; off < 16; off <<= 1) {
        p0 += __shfl_xor(p0, off);
        p1 += __shfl_xor(p1, off);
      }
      if ((lane & 15) == 0) {
        int rowl = wm + mi * 16 + ((lane >> 4) << 2) + r;
        part[wn >> 6][rowl][0] = p0;
        part[wn >> 6][rowl][1] = p1;
      }
    }
  }
  __syncthreads();
  if (threadIdx.x < 128) {
    int rowl = threadIdx.x;
    float l0 = part[0][rowl][0] + part[1][rowl][0] + b_out[z * 2 + 0];
    float l1 = part[0][rowl][1] + part[1][rowl][1] + b_out[z * 2 + 1];
    float mx = fmaxf(l0, l1);
    float e0 = expf(l0 - mx), e1 = expf(l1 - mx);
    float inv = 1.f / (e0 + e1);
    float p0 = fminf(fmaxf(e0 * inv, 1e-15f), 1.0f);
    float p1 = fminf(fmaxf(e1 * inv, 1e-15f), 1.0f);
    size_t o = ((size_t)z * B_ + m0 + rowl) * 2;
    out[o] = p0; out[o + 1] = p1;
  }
}

// PREP: cast x; e-major task panel WT0T; WT0SH [s*256+e][512];
// WT0G [32][512] (26 gate rows + zero pad); WT1, WTW, WG1T + biases.
__global__ void k_prep(const float* __restrict__ x,
    const float* __restrict__ w_task0, const float* __restrict__ b_task0,
    const float* __restrict__ w_sh0,   const float* __restrict__ b_sh0,
    const float* __restrict__ w_gate0, const float* __restrict__ b_gate0,
    const float* __restrict__ w_gsh0,  const float* __restrict__ b_gsh0,
    const float* __restrict__ w_task1, const float* __restrict__ b_task1,
    const float* __restrict__ w_sh1,   const float* __restrict__ b_sh1,
    const float* __restrict__ w_gate1, const float* __restrict__ w_tw,
    u16* __restrict__ xb, u16* __restrict__ WT0T, float* __restrict__ bias0t,
    u16* __restrict__ WT0SH, float* __restrict__ bias0sh,
    u16* __restrict__ WT0G, float* __restrict__ bias0g,
    u16* __restrict__ Wt1, float* __restrict__ bias1,
    u16* __restrict__ Wtw, float* __restrict__ WG1T)
{
  size_t i = (size_t)blockIdx.x * 256 + threadIdx.x;
  const size_t S_X8  = (size_t)16384 * 512 / 8; // 1048576
  const size_t S_T   = (size_t)2048 * 512;      // 1048576
  const size_t S_BT  = 2048;
  const size_t S_SH  = (size_t)512 * 512;       // 262144
  const size_t S_BSH = 512;
  const size_t S_G   = (size_t)32 * 512;        // 16384
  const size_t S_BG  = 32;
  const size_t S_WT1 = (size_t)5 * 512 * 256;   // 655360
  const size_t S_B1  = 5 * 512;                 // 2560
  const size_t S_WTW = (size_t)4 * 128 * 256;   // 131072
  const size_t S_WG1 = 4096;

  if (i < S_X8) {
    size_t o = i * 8;
    float4 a = *(const float4*)(x + o);
    float4 b = *(const float4*)(x + o + 4);
    u16x8 v;
    v[0] = f2b(a.x); v[1] = f2b(a.y); v[2] = f2b(a.z); v[3] = f2b(a.w);
    v[4] = f2b(b.x); v[5] = f2b(b.y); v[6] = f2b(b.z); v[7] = f2b(b.w);
    *(u16x8*)(xb + o) = v;
    return;
  }
  i -= S_X8;
  if (i < S_T) {       // e-major task experts: col c = e*8 + te
    int c = (int)(i / 512), f = (int)(i % 512);
    int te = c & 7, e = c >> 3;
    WT0T[i] = f2b(w_task0[((size_t)te * 512 + f) * 256 + e]);
    return;
  }
  i -= S_T;
  if (i < S_BT) {
    int te = (int)i & 7, e = (int)i >> 3;
    bias0t[i] = b_task0[te * 256 + e];
    return;
  }
  i -= S_BT;
  if (i < S_SH) {      // row = s*256 + e
    int row = (int)(i / 512), f = (int)(i % 512);
    int s = row >> 8, e = row & 255;
    WT0SH[i] = f2b(w_sh0[((size_t)s * 512 + f) * 256 + e]);
    return;
  }
  i -= S_SH;
  if (i < S_BSH) {
    bias0sh[i] = b_sh0[i];
    return;
  }
  i -= S_BSH;
  if (i < S_G) {
    int g = (int)(i / 512), f = (int)(i % 512);
    float v = 0.f;
    if (g < 16)      { int t = g >> 2, gg = g & 3; v = w_gate0[((size_t)t * 512 + f) * 4 + gg]; }
    else if (g < 26) { v = w_gsh0[(size_t)f * 10 + (g - 16)]; }
    WT0G[i] = f2b(v);
    return;
  }
  i -= S_G;
  if (i < S_BG) {
    int g = (int)i;
    bias0g[g] = (g < 16) ? b_gate0[g] : ((g < 26) ? b_gsh0[g - 16] : 0.f);
    return;
  }
  i -= S_BG;
  if (i < S_WT1) {
    int z = (int)(i / (512 * 256)); int rem = (int)(i % (512 * 256));
    int c = rem / 256, f = rem % 256;
    float v;
    if (z < 4) { int ee = c >> 8, o = c & 255; v = w_task1[(((size_t)(z * 2 + ee)) * 256 + f) * 256 + o]; }
    else       { int s = c >> 8, o = c & 255; v = w_sh1[((size_t)s * 256 + f) * 256 + o]; }
    Wt1[i] = f2b(v);
    return;
  }
  i -= S_WT1;
  if (i < S_B1) {
    int z = (int)(i / 512); int c = (int)(i % 512);
    float v;
    if (z < 4) { int ee = c >> 8, o = c & 255; v = b_task1[(z * 2 + ee) * 256 + o]; }
    else       { int s = c >> 8, o = c & 255; v = b_sh1[s * 256 + o]; }
    bias1[(size_t)z * 512 + c] = v;
    return;
  }
  i -= S_B1;
  if (i < S_WTW) {
    int z = (int)(i / (128 * 256)); int rem = (int)(i % (128 * 256));
    int h = rem / 256, f = rem % 256;
    Wtw[i] = f2b(w_tw[((size_t)z * 256 + f) * 128 + h]);
    return;
  }
  i -= S_WTW;
  if (i < S_WG1) {
    int t = (int)(i >> 10), gg = (int)((i >> 8) & 3), e = (int)(i & 255);
    WG1T[i] = w_gate1[((size_t)t * 256 + e) * 4 + gg];
    return;
  }
}

extern "C" void kernel_launch(void* const* d_in, const int* in_sizes, int n_in,
                              void* d_out, int out_size, void* d_ws, size_t ws_size,
                              hipStream_t stream)
{
  (void)in_sizes; (void)n_in; (void)out_size; (void)ws_size;
  const float* x       = (const float*)d_in[0];
  const float* w_task0 = (const float*)d_in[1];
  const float* b_task0 = (const float*)d_in[2];
  const float* w_sh0   = (const float*)d_in[3];
  const float* b_sh0   = (const float*)d_in[4];
  const float* w_gate0 = (const float*)d_in[5];
  const float* b_gate0 = (const float*)d_in[6];
  const float* w_gsh0  = (const float*)d_in[7];
  const float* b_gsh0  = (const float*)d_in[8];
  const float* w_task1 = (const float*)d_in[9];
  const float* b_task1 = (const float*)d_in[10];
  const float* w_sh1   = (const float*)d_in[11];
  const float* b_sh1   = (const float*)d_in[12];
  const float* w_gate1 = (const float*)d_in[13];
  const float* b_gate1 = (const float*)d_in[14];
  const float* w_tw    = (const float*)d_in[15];
  const float* b_tw    = (const float*)d_in[16];
  const float* w_out   = (const float*)d_in[17];
  const float* b_out   = (const float*)d_in[18];
  float* out = (float*)d_out;

  char* ws = (char*)d_ws;
  u16*   XB     = (u16*)  (ws + 0);           //  16,777,216  [16384][512]
  u16*   SH1E   = (u16*)  (ws + 0);           //  reuses XB (first write: gemm1)
  u16*   WT0T   = (u16*)  (ws + 16777216);    //   2,097,152  [2048][512]
  float* BIAS0T = (float*)(ws + 18874368);    //       8,192  [2048]
  u16*   WT0SH  = (u16*)  (ws + 18882560);    //     524,288  [512][512]
  float* BIAS0SH= (float*)(ws + 19406848);    //       2,048  [512]
  u16*   WT0G   = (u16*)  (ws + 19408896);    //      32,768  [32][512]
  float* BIAS0G = (float*)(ws + 19441664);    //         128  [32]
  u16*   WT1    = (u16*)  (ws + 19441792);    //   1,310,720  [5][512][256]
  float* BIAS1  = (float*)(ws + 20752512);    //      10,240  [5][512]
  u16*   WTW    = (u16*)  (ws + 20762752);    //     262,144  [4][128][256]
  float* WG1T   = (float*)(ws + 21024896);    //      16,384  [4][4][256]
  u16*   T1SH   = (u16*)  (ws + 21041280);    //  41,943,040  [5][16384][256]
  u16*   E1     = (u16*)  (ws + 62984320);    //  67,108,864  [4][16384][512]
  float* G1S    = (float*)(ws + 130093184);   //   1,048,576  [16384][16]

  k_prep<<<12389, 256, 0, stream>>>(x, w_task0, b_task0, w_sh0, b_sh0,
      w_gate0, b_gate0, w_gsh0, b_gsh0, w_task1, b_task1, w_sh1, b_sh1,
      w_gate1, w_tw,
      XB, WT0T, BIAS0T, WT0SH, BIAS0SH, WT0G, BIAS0G, WT1, BIAS1, WTW, WG1T);
  k_gemm0u<<<2048, 512, 0, stream>>>(XB, WT0T, BIAS0T, WT0SH, BIAS0SH,
      WT0G, BIAS0G, T1SH);
  k_gate1<<<2048, 256, 0, stream>>>(T1SH, WG1T, b_gate1, G1S);
  k_gemm1<<<1280, 512, 0, stream>>>(T1SH, WT1, BIAS1, E1, SH1E);
  k_tower2<<<dim3(128, 1, 4), 256, 0, stream>>>(E1, SH1E, G1S, WTW, b_tw, w_out, b_out, out);
}

// Round 17
// 172.101 us; speedup vs baseline: 1.4438x; 1.0249x over previous
//
#include <hip/hip_runtime.h>

typedef unsigned short u16;
typedef __bf16 bf16x8 __attribute__((ext_vector_type(8)));
typedef float f32x4 __attribute__((ext_vector_type(4)));
typedef u16 u16x8 __attribute__((ext_vector_type(8)));

#define B_ 16384

__device__ __forceinline__ u16 f2b(float f){
  unsigned u = __builtin_bit_cast(unsigned, f);
  u = (u + 0x7FFFu + ((u >> 16) & 1u)) >> 16;   // RNE
  return (u16)u;
}
__device__ __forceinline__ float b2f(u16 v){
  return __builtin_bit_cast(float, ((unsigned)v) << 16);
}
__device__ __forceinline__ void ld8(const u16* __restrict__ p, float* f){
  u16x8 v = *(const u16x8*)p;
  #pragma unroll
  for (int j = 0; j < 8; ++j) f[j] = b2f(v[j]);
}
__device__ __forceinline__ void st8(u16* __restrict__ p, const float* f){
  u16x8 v;
  #pragma unroll
  for (int j = 0; j < 8; ++j) v[j] = f2b(f[j]);
  *(u16x8*)p = v;
}

__device__ __forceinline__ void gload16(const u16* g, u16* lds){
  __builtin_amdgcn_global_load_lds(
      (const __attribute__((address_space(1))) unsigned int*)g,
      (__attribute__((address_space(3))) unsigned int*)lds, 16, 0, 0);
}

// ===== core32 (R9/R10-proven): BM=256, BN=128, BK=32, ring-3, counted vmcnt =
// 0 bank conflicts (row-pair layout), 2 blocks/CU. The measured plateau of
// this GEMM family is ~750 TF; 9 schedule/tile variants (R3-R16) tied or lost.
__device__ __forceinline__ void core32(const u16* __restrict__ A,
                                       const u16* __restrict__ Wt,
                                       int K, int m0, int n0, int nt,
                                       u16* sm, f32x4 acc[4][4])
{
  const int tid = threadIdx.x, lane = tid & 63, wave = tid >> 6;
  const int wm = ((tid >> 7) & 3) * 64;
  const int wn = ((tid >> 6) & 1) * 64;

  #pragma unroll
  for (int m = 0; m < 4; ++m)
    #pragma unroll
    for (int n = 0; n < 4; ++n) acc[m][n] = (f32x4){0.f, 0.f, 0.f, 0.f};

  const int s_    = (lane & 7) ^ ((lane >> 3) & 7);
  const int srow2 = 2 * (lane >> 3) + (s_ >> 2);
  const int sk    = (s_ & 3) * 8;
  const u16* gsrc[3];
  int gdst[3];
  #pragma unroll
  for (int i = 0; i < 3; ++i) {
    int c = wave * 3 + i;
    if (c < 16) {
      gsrc[i] = A + (size_t)(m0 + c * 16 + srow2) * K + sk;
      gdst[i] = c * 512;
    } else {
      gsrc[i] = Wt + (size_t)(n0 + (c - 16) * 16 + srow2) * K + sk;
      gdst[i] = 8192 + (c - 16) * 512;
    }
  }

  int aoff[4], boff[4];
  #pragma unroll
  for (int m = 0; m < 4; ++m) {
    int r = wm + m * 16 + (lane & 15);
    int L = r >> 1;
    int phys = (((r & 1) << 2) + (lane >> 4)) ^ (L & 7);
    aoff[m] = L * 64 + phys * 8;
  }
  #pragma unroll
  for (int n = 0; n < 4; ++n) {
    int r = wn + n * 16 + (lane & 15);
    int L = r >> 1;
    int phys = (((r & 1) << 2) + (lane >> 4)) ^ (L & 7);
    boff[n] = 8192 + L * 64 + phys * 8;
  }

  #pragma unroll
  for (int j = 0; j < 2; ++j) {
    u16* sl = sm + j * 12288;
    #pragma unroll
    for (int i = 0; i < 3; ++i) gload16(gsrc[i] + j * 32, sl + gdst[i]);
  }
  asm volatile("s_waitcnt vmcnt(3)" ::: "memory");
  __builtin_amdgcn_s_barrier();

  int cs = 0;
  for (int j = 0; j < nt; ++j) {
    if (j + 2 < nt) {
      int ns = cs + 2; ns = (ns >= 3) ? ns - 3 : ns;
      u16* sl = sm + ns * 12288;
      #pragma unroll
      for (int i = 0; i < 3; ++i) gload16(gsrc[i] + (size_t)(j + 2) * 32, sl + gdst[i]);
    }
    const u16* sa = sm + cs * 12288;
    bf16x8 av[4], bv[4];
    #pragma unroll
    for (int m = 0; m < 4; ++m) av[m] = *(const bf16x8*)(sa + aoff[m]);
    #pragma unroll
    for (int n = 0; n < 4; ++n) bv[n] = *(const bf16x8*)(sa + boff[n]);
    __builtin_amdgcn_s_setprio(1);
    #pragma unroll
    for (int m = 0; m < 4; ++m)
      #pragma unroll
      for (int n = 0; n < 4; ++n)
        acc[m][n] = __builtin_amdgcn_mfma_f32_16x16x32_bf16(av[m], bv[n], acc[m][n], 0, 0, 0);
    __builtin_amdgcn_s_setprio(0);
    if (j + 2 < nt)      asm volatile("s_waitcnt vmcnt(3)" ::: "memory");
    else if (j + 1 < nt) asm volatile("s_waitcnt vmcnt(0)" ::: "memory");
    __builtin_amdgcn_s_barrier();
    cs = (cs == 2) ? 0 : cs + 1;
  }
}

// ---------------- stage kernels ----------------

// GEMM0: xb[16384,512] x Wt0[2688used,512]^T. grid 1344 = 64 m x 21 n.
__global__ __launch_bounds__(512) void k_gemm0(const u16* __restrict__ xb,
    const u16* __restrict__ Wt0, const float* __restrict__ bias0,
    u16* __restrict__ E0, float* __restrict__ G0L)
{
  __shared__ __align__(16) u16 sm[36864];
  f32x4 acc[4][4];
  const int bid = blockIdx.x;                 // 1344 = 8 * 168
  const int swz = (bid & 7) * 168 + (bid >> 3);
  const int m0 = (swz / 21) * 256, n0 = (swz % 21) * 128;
  core32(xb, Wt0, 512, m0, n0, 16, sm, acc);
  const int lane = threadIdx.x & 63;
  const int wm = ((threadIdx.x >> 7) & 3) * 64, wn = ((threadIdx.x >> 6) & 1) * 64;
  #pragma unroll
  for (int mi = 0; mi < 4; ++mi)
    #pragma unroll
    for (int ni = 0; ni < 4; ++ni) {
      int gcol = n0 + wn + ni * 16 + (lane & 15);
      float bias = bias0[gcol];
      #pragma unroll
      for (int q = 0; q < 4; ++q) {
        int grow = m0 + wm + mi * 16 + ((lane >> 4) << 2) + q;
        float v = acc[mi][ni][q] + bias;
        if (gcol < 2560)      E0[(size_t)grow * 2560 + gcol] = f2b(fmaxf(v, 0.f));
        else if (gcol < 2586) G0L[(size_t)grow * 26 + (gcol - 2560)] = v;
      }
    }
}

// MIX0 + fused gate1: 8 rows/block, one 32-lane half-wave per row.
__global__ __launch_bounds__(256) void k_mix0(const u16* __restrict__ E0,
    const float* __restrict__ G0L, const float* __restrict__ WG1T,
    const float* __restrict__ b_gate1, u16* __restrict__ T1SH,
    float* __restrict__ G1S)
{
  const int b = blockIdx.x * 8 + (threadIdx.x >> 5);
  const int e0 = (threadIdx.x & 31) * 8;
  const float* gl = G0L + (size_t)b * 26;
  float g[4][4];
  #pragma unroll
  for (int t = 0; t < 4; ++t) {
    float l0 = gl[t*4+0], l1 = gl[t*4+1], l2 = gl[t*4+2], l3 = gl[t*4+3];
    float m = fmaxf(fmaxf(l0, l1), fmaxf(l2, l3));
    float e0e = expf(l0-m), e1 = expf(l1-m), e2 = expf(l2-m), e3 = expf(l3-m);
    float inv = 1.f / (e0e + e1 + e2 + e3);
    g[t][0] = e0e*inv; g[t][1] = e1*inv; g[t][2] = e2*inv; g[t][3] = e3*inv;
  }
  float gs[10];
  {
    float m = gl[16];
    #pragma unroll
    for (int j = 1; j < 10; ++j) m = fmaxf(m, gl[16 + j]);
    float s = 0.f;
    #pragma unroll
    for (int j = 0; j < 10; ++j) { gs[j] = expf(gl[16 + j] - m); s += gs[j]; }
    float inv = 1.f / s;
    #pragma unroll
    for (int j = 0; j < 10; ++j) gs[j] *= inv;
  }
  const u16* row = E0 + (size_t)b * 2560;
  float sh0[8], sh1[8], shacc[8];
  ld8(row + 2048 + e0, sh0);
  ld8(row + 2304 + e0, sh1);
  #pragma unroll
  for (int j = 0; j < 8; ++j) shacc[j] = gs[8]*sh0[j] + gs[9]*sh1[j];
  float gp[16];
  #pragma unroll
  for (int t = 0; t < 4; ++t) {
    float te0[8], te1[8], v[8];
    ld8(row + (t*2+0)*256 + e0, te0);
    ld8(row + (t*2+1)*256 + e0, te1);
    #pragma unroll
    for (int j = 0; j < 8; ++j) {
      v[j] = g[t][0]*te0[j] + g[t][1]*te1[j] + g[t][2]*sh0[j] + g[t][3]*sh1[j];
      shacc[j] += gs[t*2+0]*te0[j] + gs[t*2+1]*te1[j];
    }
    st8(T1SH + ((size_t)t * B_ + b) * 256 + e0, v);
    #pragma unroll
    for (int gg = 0; gg < 4; ++gg) {
      const float* wv = WG1T + ((size_t)(t * 4 + gg) * 256 + e0);
      float s = 0.f;
      #pragma unroll
      for (int j = 0; j < 8; ++j) s += v[j] * wv[j];
      gp[t * 4 + gg] = s;
    }
  }
  st8(T1SH + ((size_t)4 * B_ + b) * 256 + e0, shacc);
  #pragma unroll
  for (int i = 0; i < 16; ++i) {
    #pragma unroll
    for (int off = 1; off < 32; off <<= 1)
      gp[i] += __shfl_xor(gp[i], off, 32);
  }
  if ((threadIdx.x & 31) == 0) {
    float* orow = G1S + (size_t)b * 16;
    #pragma unroll
    for (int z = 0; z < 4; ++z) {
      float l0 = gp[z*4+0] + b_gate1[z*4+0];
      float l1 = gp[z*4+1] + b_gate1[z*4+1];
      float l2 = gp[z*4+2] + b_gate1[z*4+2];
      float l3 = gp[z*4+3] + b_gate1[z*4+3];
      float m = fmaxf(fmaxf(l0, l1), fmaxf(l2, l3));
      float x0 = expf(l0-m), x1 = expf(l1-m), x2 = expf(l2-m), x3 = expf(l3-m);
      float inv = 1.f / (x0 + x1 + x2 + x3);
      orow[z*4+0] = x0*inv; orow[z*4+1] = x1*inv;
      orow[z*4+2] = x2*inv; orow[z*4+3] = x3*inv;
    }
  }
}

// GEMM1: 20 panels (z 0..4 x 4 n-tiles of 128) x 64 m-blocks.
__global__ __launch_bounds__(512) void k_gemm1(const u16* __restrict__ T1SH,
    const u16* __restrict__ Wt1, const float* __restrict__ bias1,
    u16* __restrict__ E1, u16* __restrict__ SH1E)
{
  __shared__ __align__(16) u16 sm[36864];
  f32x4 acc[4][4];
  const int bid = blockIdx.x;                 // 1280 = 8 * 160
  const int swz = (bid & 7) * 160 + (bid >> 3);
  const int mi_ = swz / 20, pan = swz % 20;
  const int z  = pan >> 2;
  const int n0 = (pan & 3) * 128;
  const int m0 = mi_ * 256;
  core32(T1SH + (size_t)z * B_ * 256, Wt1 + (size_t)z * 512 * 256, 256, m0, n0, 8, sm, acc);
  const int lane = threadIdx.x & 63;
  const int wm = ((threadIdx.x >> 7) & 3) * 64, wn = ((threadIdx.x >> 6) & 1) * 64;
  const float* bias = bias1 + z * 512;
  #pragma unroll
  for (int mi = 0; mi < 4; ++mi)
    #pragma unroll
    for (int ni = 0; ni < 4; ++ni) {
      int gcol = n0 + wn + ni * 16 + (lane & 15);
      float bv = bias[gcol];
      #pragma unroll
      for (int q = 0; q < 4; ++q) {
        int grow = m0 + wm + mi * 16 + ((lane >> 4) << 2) + q;
        float v = fmaxf(acc[mi][ni][q] + bv, 0.f);
        if (z < 4) E1[((size_t)z * B_ + grow) * 512 + gcol] = f2b(v);
        else       SH1E[(size_t)grow * 512 + gcol] = f2b(v);
      }
    }
}

// TOWER2 (mix1 fused): A-tile = t2[z] built during reg-staging from E1/SH1E/G1S.
__global__ __launch_bounds__(256) void k_tower2(const u16* __restrict__ E1,
    const u16* __restrict__ SH1E, const float* __restrict__ G1S,
    const u16* __restrict__ Wtw, const float* __restrict__ b_tw,
    const float* __restrict__ w_out, const float* __restrict__ b_out,
    float* __restrict__ out)
{
  __shared__ __align__(16) u16 sm[32768];
  __shared__ float part[2][128][2];
  f32x4 acc[4][4];
  const int z = blockIdx.z;
  const int m0 = blockIdx.x * 128;
  const int tid = threadIdx.x, lane = tid & 63, wave = tid >> 6;
  const int wm = ((tid >> 7) & 1) * 64, wn = ((tid >> 6) & 1) * 64;

  #pragma unroll
  for (int mi = 0; mi < 4; ++mi)
    #pragma unroll
    for (int ni = 0; ni < 4; ++ni) acc[mi][ni] = (f32x4){0.f, 0.f, 0.f, 0.f};

  const int srow  = lane >> 3;
  const int gslot = (lane & 7) ^ srow;
  const int koff0 = gslot * 8;

  int growA[4], adst[4], bdst[4];
  const u16* bsrc[4];
  #pragma unroll
  for (int i = 0; i < 4; ++i) {
    int c = wave * 4 + i;
    growA[i] = m0 + c * 8 + srow;
    adst[i]  = c * 512;
    bsrc[i]  = Wtw + (size_t)z * 128 * 256 + (size_t)(c * 8 + srow) * 256 + koff0;
    bdst[i]  = 8192 + c * 512;
  }
  const u16* E1z = E1 + (size_t)z * B_ * 512;

  int aoff[2][4], boff[2][4];
  #pragma unroll
  for (int kk = 0; kk < 2; ++kk) {
    #pragma unroll
    for (int m = 0; m < 4; ++m) {
      int r = wm + m * 16 + (lane & 15);
      aoff[kk][m] = r * 64 + (((kk * 4 + (lane >> 4)) ^ (r & 7)) * 8);
    }
    #pragma unroll
    for (int n = 0; n < 4; ++n) {
      int r = wn + n * 16 + (lane & 15);
      boff[kk][n] = 8192 + r * 64 + (((kk * 4 + (lane >> 4)) ^ (r & 7)) * 8);
    }
  }

  #define STAGE_T(J, BUF) do {                                                 \
    u16* buf_ = (BUF);                                                         \
    _Pragma("unroll")                                                          \
    for (int i_ = 0; i_ < 4; ++i_) {                                           \
      size_t eoff_ = (size_t)growA[i_] * 512 + (J) * 64 + koff0;               \
      u16x8 ea_ = *(const u16x8*)(E1z + eoff_);                                \
      u16x8 eb_ = *(const u16x8*)(E1z + eoff_ + 256);                          \
      u16x8 sa_ = *(const u16x8*)(SH1E + eoff_);                               \
      u16x8 sb_ = *(const u16x8*)(SH1E + eoff_ + 256);                         \
      float4 g_ = *(const float4*)(G1S + (size_t)growA[i_] * 16 + z * 4);      \
      u16x8 o_;                                                                \
      _Pragma("unroll")                                                        \
      for (int jj_ = 0; jj_ < 8; ++jj_)                                        \
        o_[jj_] = f2b(g_.x * b2f(ea_[jj_]) + g_.y * b2f(eb_[jj_])              \
                    + g_.z * b2f(sa_[jj_]) + g_.w * b2f(sb_[jj_]));            \
      *(uint4*)(buf_ + adst[i_] + lane * 8) = __builtin_bit_cast(uint4, o_);   \
      gload16(bsrc[i_] + (J) * 64, buf_ + bdst[i_]);                           \
    }                                                                          \
  } while (0)

  STAGE_T(0, sm);
  __syncthreads();

  #pragma unroll
  for (int t = 0; t < 4; ++t) {
    if (t + 1 < 4) STAGE_T(t + 1, sm + ((t + 1) & 1) * 16384);
    const u16* sa = sm + (t & 1) * 16384;
    #pragma unroll
    for (int kk = 0; kk < 2; ++kk) {
      bf16x8 av[4], bv[4];
      #pragma unroll
      for (int m = 0; m < 4; ++m) av[m] = *(const bf16x8*)(sa + aoff[kk][m]);
      #pragma unroll
      for (int n = 0; n < 4; ++n) bv[n] = *(const bf16x8*)(sa + boff[kk][n]);
      #pragma unroll
      for (int m = 0; m < 4; ++m)
        #pragma unroll
        for (int n = 0; n < 4; ++n)
          acc[m][n] = __builtin_amdgcn_mfma_f32_16x16x32_bf16(av[m], bv[n], acc[m][n], 0, 0, 0);
    }
    if (t + 1 < 4) __syncthreads();
  }
  #undef STAGE_T

  #pragma unroll
  for (int mi = 0; mi < 4; ++mi) {
    #pragma unroll
    for (int r = 0; r < 4; ++r) {
      float p0 = 0.f, p1 = 0.f;
      #pragma unroll
      for (int ni = 0; ni < 4; ++ni) {
        int col = wn + ni * 16 + (lane & 15);
        float h = fmaxf(acc[mi][ni][r] + b_tw[z * 128 + col], 0.f);
        p0 += h * w_out[(z * 128 + col) * 2 + 0];
        p1 += h * w_out[(z * 128 + col) * 2 + 1];
      }
      #pragma unroll
      for (int off = 1; off < 16; off <<= 1) {
        p0 += __shfl_xor(p0, off);
        p1 += __shfl_xor(p1, off);
      }
      if ((lane & 15) == 0) {
        int rowl = wm + mi * 16 + ((lane >> 4) << 2) + r;
        part[wn >> 6][rowl][0] = p0;
        part[wn >> 6][rowl][1] = p1;
      }
    }
  }
  __syncthreads();
  if (threadIdx.x < 128) {
    int rowl = threadIdx.x;
    float l0 = part[0][rowl][0] + part[1][rowl][0] + b_out[z * 2 + 0];
    float l1 = part[0][rowl][1] + part[1][rowl][1] + b_out[z * 2 + 1];
    float mx = fmaxf(l0, l1);
    float e0 = expf(l0 - mx), e1 = expf(l1 - mx);
    float inv = 1.f / (e0 + e1);
    float p0 = fminf(fmaxf(e0 * inv, 1e-15f), 1.0f);
    float p1 = fminf(fmaxf(e1 * inv, 1e-15f), 1.0f);
    size_t o = ((size_t)z * B_ + m0 + rowl) * 2;
    out[o] = p0; out[o + 1] = p1;
  }
}

// PREP: cast x -> bf16; weight panels + biases + WG1T.
__global__ void k_prep(const float* __restrict__ x,
    const float* __restrict__ w_task0, const float* __restrict__ b_task0,
    const float* __restrict__ w_sh0,   const float* __restrict__ b_sh0,
    const float* __restrict__ w_gate0, const float* __restrict__ b_gate0,
    const float* __restrict__ w_gsh0,  const float* __restrict__ b_gsh0,
    const float* __restrict__ w_task1, const float* __restrict__ b_task1,
    const float* __restrict__ w_sh1,   const float* __restrict__ b_sh1,
    const float* __restrict__ w_gate1, const float* __restrict__ w_tw,
    u16* __restrict__ xb, u16* __restrict__ Wt0, float* __restrict__ bias0,
    u16* __restrict__ Wt1, float* __restrict__ bias1, u16* __restrict__ Wtw,
    float* __restrict__ WG1T)
{
  size_t i = (size_t)blockIdx.x * 256 + threadIdx.x;
  const size_t S_X8  = (size_t)16384 * 512 / 8; // 1048576
  const size_t S_WT0 = (size_t)2816 * 512;      // 1441792
  const size_t S_B0  = 2816;
  const size_t S_WT1 = (size_t)5 * 512 * 256;   // 655360
  const size_t S_B1  = 5 * 512;                 // 2560
  const size_t S_WTW = (size_t)4 * 128 * 256;   // 131072
  const size_t S_WG1 = 4096;

  if (i < S_X8) {
    size_t o = i * 8;
    float4 a = *(const float4*)(x + o);
    float4 b = *(const float4*)(x + o + 4);
    u16x8 v;
    v[0] = f2b(a.x); v[1] = f2b(a.y); v[2] = f2b(a.z); v[3] = f2b(a.w);
    v[4] = f2b(b.x); v[5] = f2b(b.y); v[6] = f2b(b.z); v[7] = f2b(b.w);
    *(u16x8*)(xb + o) = v;
    return;
  }
  i -= S_X8;
  if (i < S_WT0) {
    int c = (int)(i / 512), f = (int)(i % 512);
    float v = 0.f;
    if (c < 2048)      { int te = c >> 8, o = c & 255; v = w_task0[((size_t)te * 512 + f) * 256 + o]; }
    else if (c < 2560) { int s = (c - 2048) >> 8, o = c & 255; v = w_sh0[((size_t)s * 512 + f) * 256 + o]; }
    else if (c < 2576) { int q = c - 2560; int t = q >> 2, gg = q & 3; v = w_gate0[((size_t)t * 512 + f) * 4 + gg]; }
    else if (c < 2586) { int j = c - 2576; v = w_gsh0[(size_t)f * 10 + j]; }
    Wt0[i] = f2b(v);
    return;
  }
  i -= S_WT0;
  if (i < S_B0) {
    int c = (int)i; float v = 0.f;
    if (c < 2048)      { int te = c >> 8, o = c & 255; v = b_task0[te * 256 + o]; }
    else if (c < 2560) { int s = (c - 2048) >> 8, o = c & 255; v = b_sh0[s * 256 + o]; }
    else if (c < 2576) { v = b_gate0[c - 2560]; }
    else if (c < 2586) { v = b_gsh0[c - 2576]; }
    bias0[c] = v;
    return;
  }
  i -= S_B0;
  if (i < S_WT1) {
    int z = (int)(i / (512 * 256)); int rem = (int)(i % (512 * 256));
    int c = rem / 256, f = rem % 256;
    float v;
    if (z < 4) { int ee = c >> 8, o = c & 255; v = w_task1[(((size_t)(z * 2 + ee)) * 256 + f) * 256 + o]; }
    else       { int s = c >> 8, o = c & 255; v = w_sh1[((size_t)s * 256 + f) * 256 + o]; }
    Wt1[i] = f2b(v);
    return;
  }
  i -= S_WT1;
  if (i < S_B1) {
    int z = (int)(i / 512); int c = (int)(i % 512);
    float v;
    if (z < 4) { int ee = c >> 8, o = c & 255; v = b_task1[(z * 2 + ee) * 256 + o]; }
    else       { int s = c >> 8, o = c & 255; v = b_sh1[s * 256 + o]; }
    bias1[(size_t)z * 512 + c] = v;
    return;
  }
  i -= S_B1;
  if (i < S_WTW) {
    int z = (int)(i / (128 * 256)); int rem = (int)(i % (128 * 256));
    int h = rem / 256, f = rem % 256;
    Wtw[i] = f2b(w_tw[((size_t)z * 256 + f) * 128 + h]);
    return;
  }
  i -= S_WTW;
  if (i < S_WG1) {
    int t = (int)(i >> 10), gg = (int)((i >> 8) & 3), e = (int)(i & 255);
    WG1T[i] = w_gate1[((size_t)t * 256 + e) * 4 + gg];
    return;
  }
}

extern "C" void kernel_launch(void* const* d_in, const int* in_sizes, int n_in,
                              void* d_out, int out_size, void* d_ws, size_t ws_size,
                              hipStream_t stream)
{
  (void)in_sizes; (void)n_in; (void)out_size; (void)ws_size;
  const float* x       = (const float*)d_in[0];
  const float* w_task0 = (const float*)d_in[1];
  const float* b_task0 = (const float*)d_in[2];
  const float* w_sh0   = (const float*)d_in[3];
  const float* b_sh0   = (const float*)d_in[4];
  const float* w_gate0 = (const float*)d_in[5];
  const float* b_gate0 = (const float*)d_in[6];
  const float* w_gsh0  = (const float*)d_in[7];
  const float* b_gsh0  = (const float*)d_in[8];
  const float* w_task1 = (const float*)d_in[9];
  const float* b_task1 = (const float*)d_in[10];
  const float* w_sh1   = (const float*)d_in[11];
  const float* b_sh1   = (const float*)d_in[12];
  const float* w_gate1 = (const float*)d_in[13];
  const float* b_gate1 = (const float*)d_in[14];
  const float* w_tw    = (const float*)d_in[15];
  const float* b_tw    = (const float*)d_in[16];
  const float* w_out   = (const float*)d_in[17];
  const float* b_out   = (const float*)d_in[18];
  float* out = (float*)d_out;

  char* ws = (char*)d_ws;
  u16*   XB    = (u16*)  (ws + 0);            //  16,777,216  [16384][512] (dead after gemm0/mix0)
  u16*   SH1E  = (u16*)  (ws + 0);            //  reuses XB (first write: gemm1)
  u16*   WT0   = (u16*)  (ws + 16777216);     //   2,883,584  [2816][512]
  float* BIAS0 = (float*)(ws + 19660800);     //      11,264  [2816]
  u16*   WT1   = (u16*)  (ws + 19672064);     //   1,310,720  [5][512][256]
  float* BIAS1 = (float*)(ws + 20982784);     //      10,240  [5][512]
  u16*   WTW   = (u16*)  (ws + 20993024);     //     262,144  [4][128][256]
  u16*   E0    = (u16*)  (ws + 21255168);     //  83,886,080  [16384][2560]
  float* G0L   = (float*)(ws + 105141248);    //   1,703,936  [16384][26]
  u16*   T1SH  = (u16*)  (ws + 106845184);    //  41,943,040  [5][16384][256]
  u16*   E1    = (u16*)  (ws + 148788224);    //  67,108,864  [4][16384][512]
  float* G1S   = (float*)(ws + 215897088);    //   1,048,576  [16384][16]
  float* WG1T  = (float*)(ws + 216945664);    //      16,384  [4][4][256]

  k_prep<<<12837, 256, 0, stream>>>(x, w_task0, b_task0, w_sh0, b_sh0, w_gate0, b_gate0,
      w_gsh0, b_gsh0, w_task1, b_task1, w_sh1, b_sh1, w_gate1, w_tw,
      XB, WT0, BIAS0, WT1, BIAS1, WTW, WG1T);
  k_gemm0<<<1344, 512, 0, stream>>>(XB, WT0, BIAS0, E0, G0L);
  k_mix0<<<2048, 256, 0, stream>>>(E0, G0L, WG1T, b_gate1, T1SH, G1S);
  k_gemm1<<<1280, 512, 0, stream>>>(T1SH, WT1, BIAS1, E1, SH1E);
  k_tower2<<<dim3(128, 1, 4), 256, 0, stream>>>(E1, SH1E, G1S, WTW, b_tw, w_out, b_out, out);
}